// Round 1
// baseline (1744.950 us; speedup 1.0000x reference)
//
#include <hip/hip_runtime.h>
#include <hip/hip_fp16.h>
#include <cstdint>
#include <cstddef>

// ---------------------------------------------------------------------------
// f16x2 helpers: v_dot2_f32_f16 (2 MAC/inst, f32 accumulate)
// ---------------------------------------------------------------------------
typedef _Float16 hh2 __attribute__((ext_vector_type(2)));

__device__ __forceinline__ float fdot2u(unsigned a, unsigned b, float c) {
#if __has_builtin(__builtin_amdgcn_fdot2)
    return __builtin_amdgcn_fdot2(__builtin_bit_cast(hh2, a),
                                  __builtin_bit_cast(hh2, b), c, false);
#else
    float r;
    asm("v_dot2_f32_f16 %0, %1, %2, %3" : "=v"(r) : "v"(a), "v"(b), "v"(c));
    return r;
#endif
}

__device__ __forceinline__ unsigned packh2f(float x, float y) {
    hh2 v;
    v.x = (_Float16)x;
    v.y = (_Float16)y;
    return __builtin_bit_cast(unsigned, v);
}

__device__ __forceinline__ float sigmoidf_fast(float x) {
    // 1/(1+e^-x); x=-90 -> exp=inf -> rcp(inf)=0 (correct), no NaN path
    return __builtin_amdgcn_rcpf(1.f + __expf(-x));
}
__device__ __forceinline__ float tanhf_fast(float x) {
    // clamp avoids (1-inf)*0 = NaN for x < -44
    float e = __expf(-2.f * fmaxf(x, -30.f));
    return (1.f - e) * __builtin_amdgcn_rcpf(1.f + e);
}

// ---------------------------------------------------------------------------
// Kernel A: xp[row][g] = f16( sum_k x[row][k]*W[k][g] + b[g] ),  row=b*T+t
// 512 threads: thread g owns column g, W column packed in 32 VGPRs.
// ---------------------------------------------------------------------------
__global__ __launch_bounds__(512)
void k_xproj(const float* __restrict__ x, const float* __restrict__ W,
             const float* __restrict__ bias, __half* __restrict__ xp, int rows)
{
    __shared__ __align__(16) unsigned xrow[32];
    const int g = threadIdx.x;

    unsigned wcol[32];
#pragma unroll
    for (int k2 = 0; k2 < 32; ++k2)
        wcol[k2] = packh2f(W[(2*k2)*512 + g], W[(2*k2+1)*512 + g]);
    const float bg = bias[g];

    for (int row = blockIdx.x; row < rows; row += gridDim.x) {
        if (g < 32) {
            float2 xv = ((const float2*)(x + (size_t)row * 64))[g];
            xrow[g] = packh2f(xv.x, xv.y);
        }
        __syncthreads();
        float a0 = bg, a1 = 0.f, a2 = 0.f, a3 = 0.f;
        const uint4* xr = (const uint4*)xrow;
#pragma unroll
        for (int k8 = 0; k8 < 8; ++k8) {
            uint4 v = xr[k8];
            a0 = fdot2u(v.x, wcol[4*k8+0], a0);
            a1 = fdot2u(v.y, wcol[4*k8+1], a1);
            a2 = fdot2u(v.z, wcol[4*k8+2], a2);
            a3 = fdot2u(v.w, wcol[4*k8+3], a3);
        }
        xp[(size_t)row * 512 + g] = __float2half((a0 + a1) + (a2 + a3));
        __syncthreads();
    }
}

// ---------------------------------------------------------------------------
// Kernel B: the LSTM recurrence. One block per batch element, 512 threads.
// Thread g computes gate column g: z[g] = xp[t][g] + sum_k h[k]*U[k][g].
// h kept packed f16x2 in LDS (broadcast reads); U column in 64 VGPRs.
// All threads redundantly compute c/h update (keeps waves balanced);
// only gate-0 threads (g<128) write h to LDS and hs to global.
// FUSE_XP variant computes x@W+b on the fly (used when ws is small).
// ---------------------------------------------------------------------------
template<bool FUSE_XP>
__global__ __launch_bounds__(512)
void k_lstm(const float* __restrict__ U,
            const __half* __restrict__ xp,
            const float* __restrict__ x,
            const float* __restrict__ W,
            const float* __restrict__ bias,
            __half* __restrict__ hs, int T)
{
    __shared__ __align__(16) unsigned hbuf[64];   // h as 64 packed f16x2
    __shared__ float act[512];                    // gate activations
    __shared__ __align__(16) unsigned xrow[32];   // FUSE_XP: x row packed

    const int g    = threadIdx.x;
    const int bb   = blockIdx.x;
    const int j    = g & 127;
    const int gate = g >> 7;           // 0:i 1:f 2:g 3:o (wave-uniform)

    unsigned ucol[64];
#pragma unroll
    for (int k2 = 0; k2 < 64; ++k2)
        ucol[k2] = packh2f(U[(2*k2)*512 + g], U[(2*k2+1)*512 + g]);

    unsigned wcol[32];
    float bg = 0.f;
    const float2* __restrict__ xb2 = nullptr;
    if constexpr (FUSE_XP) {
#pragma unroll
        for (int k2 = 0; k2 < 32; ++k2)
            wcol[k2] = packh2f(W[(2*k2)*512 + g], W[(2*k2+1)*512 + g]);
        bg = bias[g];
        xb2 = (const float2*)(x + (size_t)bb * T * 64);
        if (g < 32) {
            float2 x0 = xb2[g];                 // row t=0
            xrow[g] = packh2f(x0.x, x0.y);
        }
    }

    if (g < 64) hbuf[g] = 0u;
    float c = 0.f;

    const unsigned short* __restrict__ xpu =
        (const unsigned short*)xp + (FUSE_XP ? (size_t)0 : (size_t)bb * T * 512);
    __half* __restrict__ hsb = hs + (size_t)bb * T * 128;

    unsigned short xq0 = 0, xq1 = 0;            // 2-deep xp prefetch
    if constexpr (!FUSE_XP) {
        xq0 = xpu[g];
        xq1 = xpu[512 + g];
    }
    __syncthreads();

    for (int t = 0; t < T; ++t) {
        unsigned short xq2 = 0;
        float2 xn = make_float2(0.f, 0.f);
        if constexpr (!FUSE_XP) {
            if (t + 2 < T) xq2 = xpu[(size_t)(t + 2) * 512 + g];
        } else {
            if (g < 32 && t + 1 < T) xn = xb2[(size_t)(t + 1) * 32 + g];
        }

        float a0, a1 = 0.f, a2 = 0.f, a3 = 0.f;
        if constexpr (FUSE_XP) a0 = bg;
        else                   a0 = __half2float(__ushort_as_half(xq0));

        const uint4* hr = (const uint4*)hbuf;
#pragma unroll
        for (int k8 = 0; k8 < 16; ++k8) {
            uint4 v = hr[k8];
            a0 = fdot2u(v.x, ucol[4*k8+0], a0);
            a1 = fdot2u(v.y, ucol[4*k8+1], a1);
            a2 = fdot2u(v.z, ucol[4*k8+2], a2);
            a3 = fdot2u(v.w, ucol[4*k8+3], a3);
        }
        if constexpr (FUSE_XP) {
            const uint4* xr = (const uint4*)xrow;
#pragma unroll
            for (int k8 = 0; k8 < 8; ++k8) {
                uint4 v = xr[k8];
                a0 = fdot2u(v.x, wcol[4*k8+0], a0);
                a1 = fdot2u(v.y, wcol[4*k8+1], a1);
                a2 = fdot2u(v.z, wcol[4*k8+2], a2);
                a3 = fdot2u(v.w, wcol[4*k8+3], a3);
            }
        }
        float z = (a0 + a1) + (a2 + a3);

        float a = (gate == 2) ? tanhf_fast(z) : sigmoidf_fast(z);
        act[g] = a;
        __syncthreads();

        float iv = act[j];
        float fv = act[j + 128];
        float gv = act[j + 256];
        float ov = act[j + 384];
        c = fmaf(fv, c, iv * gv);              // all threads redundantly
        float h = ov * tanhf_fast(c);
        if (gate == 0) {
            ((unsigned short*)hbuf)[j] = __half_as_ushort(__float2half(h));
            hsb[(size_t)t * 128 + j] = __float2half(h);
        }
        if constexpr (FUSE_XP) {
            if (g < 32 && t + 1 < T) xrow[g] = packh2f(xn.x, xn.y);
        } else {
            xq0 = xq1; xq1 = xq2;
        }
        __syncthreads();
    }
}

// ---------------------------------------------------------------------------
// Kernel C: fc layer [rows,128] @ [128,128] (+bias, optional relu), f16 io.
// 512 threads = 4 row-slots x 128 cols; W column packed in 64 VGPRs.
// ---------------------------------------------------------------------------
template<bool RELU>
__global__ __launch_bounds__(512)
void k_fc128(const __half* __restrict__ in16, const float* __restrict__ Wg,
             const float* __restrict__ bias, __half* __restrict__ out16, int rows)
{
    __shared__ __align__(16) unsigned rowbuf[4 * 64];
    const int tid = threadIdx.x;
    const int n   = tid & 127;
    const int rs  = tid >> 7;

    unsigned wcol[64];
#pragma unroll
    for (int k2 = 0; k2 < 64; ++k2)
        wcol[k2] = packh2f(Wg[(2*k2)*128 + n], Wg[(2*k2+1)*128 + n]);
    const float bn = bias[n];

    for (int row0 = blockIdx.x * 4; row0 < rows; row0 += gridDim.x * 4) {
        if (tid < 256)
            rowbuf[tid] = ((const unsigned*)(in16 + (size_t)row0 * 128))[tid];
        __syncthreads();
        float a0 = bn, a1 = 0.f, a2 = 0.f, a3 = 0.f;
        const uint4* hr = (const uint4*)(rowbuf + rs * 64);
#pragma unroll
        for (int k8 = 0; k8 < 16; ++k8) {
            uint4 v = hr[k8];
            a0 = fdot2u(v.x, wcol[4*k8+0], a0);
            a1 = fdot2u(v.y, wcol[4*k8+1], a1);
            a2 = fdot2u(v.z, wcol[4*k8+2], a2);
            a3 = fdot2u(v.w, wcol[4*k8+3], a3);
        }
        float a = (a0 + a1) + (a2 + a3);
        if (RELU) a = fmaxf(a, 0.f);
        out16[(size_t)(row0 + rs) * 128 + n] = __float2half(a);
        __syncthreads();
    }
}

// ---------------------------------------------------------------------------
// Kernel D: fused d3 = relu(d2@W3+b3)  [rows,32], d4 = sigmoid(d3@W4+b4) -> out
// 512 threads = 16 row-slots x 32 cols.
// ---------------------------------------------------------------------------
__global__ __launch_bounds__(512)
void k_l34(const __half* __restrict__ in16, const float* __restrict__ W3,
           const float* __restrict__ b3, const float* __restrict__ W4,
           const float* __restrict__ b4, float* __restrict__ out, int rows)
{
    __shared__ __align__(16) unsigned rowbuf[16 * 64];
    __shared__ __align__(16) unsigned short d3buf[16 * 32];
    const int tid = threadIdx.x;
    const int n   = tid & 31;
    const int rs  = tid >> 5;                   // 0..15

    unsigned w3col[64];
#pragma unroll
    for (int k2 = 0; k2 < 64; ++k2)
        w3col[k2] = packh2f(W3[(2*k2)*32 + n], W3[(2*k2+1)*32 + n]);
    unsigned w4p[16];
#pragma unroll
    for (int k2 = 0; k2 < 16; ++k2)
        w4p[k2] = packh2f(W4[2*k2], W4[2*k2+1]);
    const float b3n = b3[n];
    const float b4v = b4[0];

    for (int row0 = blockIdx.x * 16; row0 < rows; row0 += gridDim.x * 16) {
        rowbuf[tid]       = ((const unsigned*)(in16 + (size_t)row0 * 128))[tid];
        rowbuf[tid + 512] = ((const unsigned*)(in16 + (size_t)row0 * 128))[tid + 512];
        __syncthreads();
        float a0 = b3n, a1 = 0.f, a2 = 0.f, a3 = 0.f;
        const uint4* hr = (const uint4*)(rowbuf + rs * 64);
#pragma unroll
        for (int k8 = 0; k8 < 16; ++k8) {
            uint4 v = hr[k8];
            a0 = fdot2u(v.x, w3col[4*k8+0], a0);
            a1 = fdot2u(v.y, w3col[4*k8+1], a1);
            a2 = fdot2u(v.z, w3col[4*k8+2], a2);
            a3 = fdot2u(v.w, w3col[4*k8+3], a3);
        }
        float a = fmaxf((a0 + a1) + (a2 + a3), 0.f);
        d3buf[rs * 32 + n] = __half_as_ushort(__float2half(a));
        __syncthreads();
        if (tid < 16) {
            const uint4* dp = (const uint4*)(d3buf + tid * 32);
            float s0 = b4v, s1 = 0.f;
#pragma unroll
            for (int q = 0; q < 4; ++q) {
                uint4 v = dp[q];
                s0 = fdot2u(v.x, w4p[4*q+0], s0);
                s1 = fdot2u(v.y, w4p[4*q+1], s1);
                s0 = fdot2u(v.z, w4p[4*q+2], s0);
                s1 = fdot2u(v.w, w4p[4*q+3], s1);
            }
            out[row0 + tid] = sigmoidf_fast(s0 + s1);
        }
        __syncthreads();
    }
}

// ---------------------------------------------------------------------------
extern "C" void kernel_launch(void* const* d_in, const int* in_sizes, int n_in,
                              void* d_out, int out_size, void* d_ws, size_t ws_size,
                              hipStream_t stream)
{
    const float* x  = (const float*)d_in[0];
    const float* W  = (const float*)d_in[1];
    const float* U  = (const float*)d_in[2];
    const float* b  = (const float*)d_in[3];
    const float* W1 = (const float*)d_in[4];
    const float* b1 = (const float*)d_in[5];
    const float* W2 = (const float*)d_in[6];
    const float* b2 = (const float*)d_in[7];
    const float* W3 = (const float*)d_in[8];
    const float* b3 = (const float*)d_in[9];
    const float* W4 = (const float*)d_in[10];
    const float* b4 = (const float*)d_in[11];
    float* out = (float*)d_out;

    const int T    = 2048;
    const int rows = in_sizes[0] / 64;     // B*T = 131072
    const int B    = rows / T;             // 64

    char* ws = (char*)d_ws;
    const size_t xp_bytes = (size_t)rows * 512 * sizeof(__half);   // 128 MiB
    const size_t hs_bytes = (size_t)rows * 128 * sizeof(__half);   //  32 MiB

    __half *xp16, *hs16, *d1, *d2;
    const bool bigws = ws_size >= xp_bytes + hs_bytes;
    if (bigws) {
        xp16 = (__half*)ws;                    // [0, 128M)
        hs16 = (__half*)(ws + xp_bytes);       // [128M, 160M)
        d1   = (__half*)ws;                    // alias xp (dead after LSTM)
        d2   = (__half*)(ws + hs_bytes);       // alias xp+32M (no overlap w/ d1)
    } else {
        xp16 = nullptr;                        // compute x@W on the fly
        hs16 = (__half*)ws;                    // [0, 32M)
        d1   = (__half*)(ws + hs_bytes);       // [32M, 64M)
        d2   = (__half*)ws;                    // alias hs (dead after L1)
    }

    if (bigws) {
        k_xproj<<<2048, 512, 0, stream>>>(x, W, b, xp16, rows);
        k_lstm<false><<<B, 512, 0, stream>>>(U, xp16, nullptr, nullptr, nullptr, hs16, T);
    } else {
        k_lstm<true><<<B, 512, 0, stream>>>(U, nullptr, x, W, b, hs16, T);
    }
    k_fc128<false><<<1024, 512, 0, stream>>>(hs16, W1, b1, d1, rows);
    k_fc128<true ><<<1024, 512, 0, stream>>>(d1,  W2, b2, d2, rows);
    k_l34<<<1024, 512, 0, stream>>>(d2, W3, b3, W4, b4, out, rows);
}

// Round 2
// 1467.620 us; speedup vs baseline: 1.1890x; 1.1890x over previous
//
#include <hip/hip_runtime.h>
#include <hip/hip_fp16.h>
#include <cstdint>
#include <cstddef>

// ---------------------------------------------------------------------------
// helpers
// ---------------------------------------------------------------------------
typedef _Float16 hh2  __attribute__((ext_vector_type(2)));
typedef _Float16 f16x8 __attribute__((ext_vector_type(8)));
typedef float    f32x4 __attribute__((ext_vector_type(4)));

__device__ __forceinline__ float fdot2u(unsigned a, unsigned b, float c) {
#if __has_builtin(__builtin_amdgcn_fdot2)
    return __builtin_amdgcn_fdot2(__builtin_bit_cast(hh2, a),
                                  __builtin_bit_cast(hh2, b), c, false);
#else
    float r;
    asm("v_dot2_f32_f16 %0, %1, %2, %3" : "=v"(r) : "v"(a), "v"(b), "v"(c));
    return r;
#endif
}

__device__ __forceinline__ unsigned packh2f(float x, float y) {
    hh2 v;
    v.x = (_Float16)x;
    v.y = (_Float16)y;
    return __builtin_bit_cast(unsigned, v);
}

__device__ __forceinline__ float sigmoidf_fast(float x) {
    return __builtin_amdgcn_rcpf(1.f + __expf(-x));
}
__device__ __forceinline__ float tanhf_fast(float x) {
    float e = __expf(-2.f * fmaxf(x, -30.f));
    return (1.f - e) * __builtin_amdgcn_rcpf(1.f + e);
}

// ---------------------------------------------------------------------------
// Kernel A: xp[row][g] = f16( sum_k x[row][k]*W[k][g] + b[g] ),  row=b*T+t
// ---------------------------------------------------------------------------
__global__ __launch_bounds__(512)
void k_xproj(const float* __restrict__ x, const float* __restrict__ W,
             const float* __restrict__ bias, __half* __restrict__ xp, int rows)
{
    __shared__ __align__(16) unsigned xrow[32];
    const int g = threadIdx.x;

    unsigned wcol[32];
#pragma unroll
    for (int k2 = 0; k2 < 32; ++k2)
        wcol[k2] = packh2f(W[(2*k2)*512 + g], W[(2*k2+1)*512 + g]);
    const float bg = bias[g];

    for (int row = blockIdx.x; row < rows; row += gridDim.x) {
        if (g < 32) {
            float2 xv = ((const float2*)(x + (size_t)row * 64))[g];
            xrow[g] = packh2f(xv.x, xv.y);
        }
        __syncthreads();
        float a0 = bg, a1 = 0.f, a2 = 0.f, a3 = 0.f;
        const uint4* xr = (const uint4*)xrow;
#pragma unroll
        for (int k8 = 0; k8 < 8; ++k8) {
            uint4 v = xr[k8];
            a0 = fdot2u(v.x, wcol[4*k8+0], a0);
            a1 = fdot2u(v.y, wcol[4*k8+1], a1);
            a2 = fdot2u(v.z, wcol[4*k8+2], a2);
            a3 = fdot2u(v.w, wcol[4*k8+3], a3);
        }
        xp[(size_t)row * 512 + g] = __float2half((a0 + a1) + (a2 + a3));
        __syncthreads();
    }
}

// ---------------------------------------------------------------------------
// Kernel B (new): MFMA LSTM. One block per batch element, 512 threads (8 waves).
// z = h @ U via mfma_f32_16x16x32_f16, M=1 (row broadcast), N=512, K=128.
// Wave w owns cols {g*128 + 16w + (lane&15)} for all 4 gates g.
// U stays in 64 VGPRs as B-fragments (loaded once). h double-buffered in LDS:
// per step per wave = 4 ds_read_b128 + 1 ds_write_b16, ONE barrier.
// All 16 rows of A are pointed at the same h data, so every lane's C-frag
// element 0 holds a valid z for its column -> gates i,f,g,o combine in-lane,
// c persists in a VGPR, no act[] LDS round-trip.
// ---------------------------------------------------------------------------
__global__ __launch_bounds__(512)
void k_lstm2(const float* __restrict__ U, const __half* __restrict__ xp,
             __half* __restrict__ hs, int T)
{
    __shared__ __align__(16) unsigned short hbuf[2][128];

    const int tid = threadIdx.x;
    const int w   = tid >> 6;        // wave 0..7
    const int l   = tid & 63;
    const int lj  = l & 15;          // col within 16-wide window
    const int hi  = l >> 4;          // quarter (k-group)
    const int bb  = blockIdx.x;

    // B-frags: B[k][n] tile is U[kk*32 + hi*8 + j][g*128 + w*16 + lj], j=0..7
    f16x8 Bf[4][4];
#pragma unroll
    for (int g = 0; g < 4; ++g) {
        const int col = g * 128 + w * 16 + lj;
#pragma unroll
        for (int kk = 0; kk < 4; ++kk) {
#pragma unroll
            for (int j = 0; j < 8; ++j)
                Bf[g][kk][j] = (_Float16)U[(size_t)(kk*32 + hi*8 + j) * 512 + col];
        }
    }

    if (tid < 128) { hbuf[0][tid] = 0; hbuf[1][tid] = 0; }

    const unsigned short* __restrict__ xpu =
        (const unsigned short*)xp + (size_t)bb * T * 512;
    __half* __restrict__ hsb = hs + (size_t)bb * T * 128;

    float c = 0.f;
    unsigned short xq[4], xqn[4];
#pragma unroll
    for (int g = 0; g < 4; ++g) xq[g] = xpu[g * 128 + w * 16 + lj];

    __syncthreads();

    int cur = 0;
    for (int t = 0; t < T; ++t) {
        // prefetch next step's xp (clamped; L2-resident, hidden under MFMA)
        const int tn = (t + 1 < T) ? t + 1 : t;
#pragma unroll
        for (int g = 0; g < 4; ++g)
            xqn[g] = xpu[(size_t)tn * 512 + g * 128 + w * 16 + lj];

        // A-frags: every quarter reads the 16B k-slice for its hi group;
        // all 16 "rows" get the same h data (row broadcast).
        f16x8 Af[4];
#pragma unroll
        for (int kk = 0; kk < 4; ++kk)
            Af[kk] = *(const f16x8*)&hbuf[cur][kk * 32 + hi * 8];

        f32x4 Cf[4];
#pragma unroll
        for (int g = 0; g < 4; ++g) {
            float z0 = __half2float(__ushort_as_half(xq[g]));
            f32x4 ci = {z0, z0, z0, z0};
            Cf[g] = ci;
        }
#pragma unroll
        for (int kk = 0; kk < 4; ++kk) {
#pragma unroll
            for (int g = 0; g < 4; ++g)
                Cf[g] = __builtin_amdgcn_mfma_f32_16x16x32_f16(Af[kk], Bf[g][kk], Cf[g], 0, 0, 0);
        }

        float iv = sigmoidf_fast(Cf[0][0]);
        float fv = sigmoidf_fast(Cf[1][0]);
        float gv = tanhf_fast(Cf[2][0]);
        float ov = sigmoidf_fast(Cf[3][0]);
        c = fmaf(fv, c, iv * gv);
        float h = ov * tanhf_fast(c);
        unsigned short hq = __half_as_ushort(__float2half(h));

        if (l < 16) {
            hbuf[cur ^ 1][w * 16 + lj] = hq;
            hsb[(size_t)t * 128 + w * 16 + lj] = __ushort_as_half(hq);
        }
#pragma unroll
        for (int g = 0; g < 4; ++g) xq[g] = xqn[g];

        __syncthreads();
        cur ^= 1;
    }
}

// ---------------------------------------------------------------------------
// Fallback LSTM (small-ws path): fused x@W on the fly, dot2-based (round-1).
// ---------------------------------------------------------------------------
__global__ __launch_bounds__(512)
void k_lstm_fused(const float* __restrict__ U,
                  const float* __restrict__ x,
                  const float* __restrict__ W,
                  const float* __restrict__ bias,
                  __half* __restrict__ hs, int T)
{
    __shared__ __align__(16) unsigned hbuf[64];
    __shared__ float act[512];
    __shared__ __align__(16) unsigned xrow[32];

    const int g    = threadIdx.x;
    const int bb   = blockIdx.x;
    const int j    = g & 127;
    const int gate = g >> 7;

    unsigned ucol[64];
#pragma unroll
    for (int k2 = 0; k2 < 64; ++k2)
        ucol[k2] = packh2f(U[(2*k2)*512 + g], U[(2*k2+1)*512 + g]);

    unsigned wcol[32];
#pragma unroll
    for (int k2 = 0; k2 < 32; ++k2)
        wcol[k2] = packh2f(W[(2*k2)*512 + g], W[(2*k2+1)*512 + g]);
    const float bg = bias[g];
    const float2* __restrict__ xb2 = (const float2*)(x + (size_t)bb * T * 64);
    if (g < 32) {
        float2 x0 = xb2[g];
        xrow[g] = packh2f(x0.x, x0.y);
    }

    if (g < 64) hbuf[g] = 0u;
    float c = 0.f;
    __half* __restrict__ hsb = hs + (size_t)bb * T * 128;
    __syncthreads();

    for (int t = 0; t < T; ++t) {
        float2 xn = make_float2(0.f, 0.f);
        if (g < 32 && t + 1 < T) xn = xb2[(size_t)(t + 1) * 32 + g];

        float a0 = bg, a1 = 0.f, a2 = 0.f, a3 = 0.f;
        const uint4* hr = (const uint4*)hbuf;
#pragma unroll
        for (int k8 = 0; k8 < 16; ++k8) {
            uint4 v = hr[k8];
            a0 = fdot2u(v.x, ucol[4*k8+0], a0);
            a1 = fdot2u(v.y, ucol[4*k8+1], a1);
            a2 = fdot2u(v.z, ucol[4*k8+2], a2);
            a3 = fdot2u(v.w, ucol[4*k8+3], a3);
        }
        const uint4* xr = (const uint4*)xrow;
#pragma unroll
        for (int k8 = 0; k8 < 8; ++k8) {
            uint4 v = xr[k8];
            a0 = fdot2u(v.x, wcol[4*k8+0], a0);
            a1 = fdot2u(v.y, wcol[4*k8+1], a1);
            a2 = fdot2u(v.z, wcol[4*k8+2], a2);
            a3 = fdot2u(v.w, wcol[4*k8+3], a3);
        }
        float z = (a0 + a1) + (a2 + a3);
        float a = (gate == 2) ? tanhf_fast(z) : sigmoidf_fast(z);
        act[g] = a;
        __syncthreads();

        float iv = act[j];
        float fv = act[j + 128];
        float gv = act[j + 256];
        float ov = act[j + 384];
        c = fmaf(fv, c, iv * gv);
        float h = ov * tanhf_fast(c);
        if (gate == 0) {
            ((unsigned short*)hbuf)[j] = __half_as_ushort(__float2half(h));
            hsb[(size_t)t * 128 + j] = __float2half(h);
        }
        if (g < 32 && t + 1 < T) xrow[g] = packh2f(xn.x, xn.y);
        __syncthreads();
    }
}

// ---------------------------------------------------------------------------
// Kernel C: fc layer [rows,128] @ [128,128] (+bias, optional relu), f16 io.
// ---------------------------------------------------------------------------
template<bool RELU>
__global__ __launch_bounds__(512)
void k_fc128(const __half* __restrict__ in16, const float* __restrict__ Wg,
             const float* __restrict__ bias, __half* __restrict__ out16, int rows)
{
    __shared__ __align__(16) unsigned rowbuf[4 * 64];
    const int tid = threadIdx.x;
    const int n   = tid & 127;
    const int rs  = tid >> 7;

    unsigned wcol[64];
#pragma unroll
    for (int k2 = 0; k2 < 64; ++k2)
        wcol[k2] = packh2f(Wg[(2*k2)*128 + n], Wg[(2*k2+1)*128 + n]);
    const float bn = bias[n];

    for (int row0 = blockIdx.x * 4; row0 < rows; row0 += gridDim.x * 4) {
        if (tid < 256)
            rowbuf[tid] = ((const unsigned*)(in16 + (size_t)row0 * 128))[tid];
        __syncthreads();
        float a0 = bn, a1 = 0.f, a2 = 0.f, a3 = 0.f;
        const uint4* hr = (const uint4*)(rowbuf + rs * 64);
#pragma unroll
        for (int k8 = 0; k8 < 16; ++k8) {
            uint4 v = hr[k8];
            a0 = fdot2u(v.x, wcol[4*k8+0], a0);
            a1 = fdot2u(v.y, wcol[4*k8+1], a1);
            a2 = fdot2u(v.z, wcol[4*k8+2], a2);
            a3 = fdot2u(v.w, wcol[4*k8+3], a3);
        }
        float a = (a0 + a1) + (a2 + a3);
        if (RELU) a = fmaxf(a, 0.f);
        out16[(size_t)(row0 + rs) * 128 + n] = __float2half(a);
        __syncthreads();
    }
}

// ---------------------------------------------------------------------------
// Kernel D: fused d3 = relu(d2@W3+b3), d4 = sigmoid(d3@W4+b4) -> out (f32)
// ---------------------------------------------------------------------------
__global__ __launch_bounds__(512)
void k_l34(const __half* __restrict__ in16, const float* __restrict__ W3,
           const float* __restrict__ b3, const float* __restrict__ W4,
           const float* __restrict__ b4, float* __restrict__ out, int rows)
{
    __shared__ __align__(16) unsigned rowbuf[16 * 64];
    __shared__ __align__(16) unsigned short d3buf[16 * 32];
    const int tid = threadIdx.x;
    const int n   = tid & 31;
    const int rs  = tid >> 5;

    unsigned w3col[64];
#pragma unroll
    for (int k2 = 0; k2 < 64; ++k2)
        w3col[k2] = packh2f(W3[(2*k2)*32 + n], W3[(2*k2+1)*32 + n]);
    unsigned w4p[16];
#pragma unroll
    for (int k2 = 0; k2 < 16; ++k2)
        w4p[k2] = packh2f(W4[2*k2], W4[2*k2+1]);
    const float b3n = b3[n];
    const float b4v = b4[0];

    for (int row0 = blockIdx.x * 16; row0 < rows; row0 += gridDim.x * 16) {
        rowbuf[tid]       = ((const unsigned*)(in16 + (size_t)row0 * 128))[tid];
        rowbuf[tid + 512] = ((const unsigned*)(in16 + (size_t)row0 * 128))[tid + 512];
        __syncthreads();
        float a0 = b3n, a1 = 0.f, a2 = 0.f, a3 = 0.f;
        const uint4* hr = (const uint4*)(rowbuf + rs * 64);
#pragma unroll
        for (int k8 = 0; k8 < 16; ++k8) {
            uint4 v = hr[k8];
            a0 = fdot2u(v.x, w3col[4*k8+0], a0);
            a1 = fdot2u(v.y, w3col[4*k8+1], a1);
            a2 = fdot2u(v.z, w3col[4*k8+2], a2);
            a3 = fdot2u(v.w, w3col[4*k8+3], a3);
        }
        float a = fmaxf((a0 + a1) + (a2 + a3), 0.f);
        d3buf[rs * 32 + n] = __half_as_ushort(__float2half(a));
        __syncthreads();
        if (tid < 16) {
            const uint4* dp = (const uint4*)(d3buf + tid * 32);
            float s0 = b4v, s1 = 0.f;
#pragma unroll
            for (int q = 0; q < 4; ++q) {
                uint4 v = dp[q];
                s0 = fdot2u(v.x, w4p[4*q+0], s0);
                s1 = fdot2u(v.y, w4p[4*q+1], s1);
                s0 = fdot2u(v.z, w4p[4*q+2], s0);
                s1 = fdot2u(v.w, w4p[4*q+3], s1);
            }
            out[row0 + tid] = sigmoidf_fast(s0 + s1);
        }
        __syncthreads();
    }
}

// ---------------------------------------------------------------------------
extern "C" void kernel_launch(void* const* d_in, const int* in_sizes, int n_in,
                              void* d_out, int out_size, void* d_ws, size_t ws_size,
                              hipStream_t stream)
{
    const float* x  = (const float*)d_in[0];
    const float* W  = (const float*)d_in[1];
    const float* U  = (const float*)d_in[2];
    const float* b  = (const float*)d_in[3];
    const float* W1 = (const float*)d_in[4];
    const float* b1 = (const float*)d_in[5];
    const float* W2 = (const float*)d_in[6];
    const float* b2 = (const float*)d_in[7];
    const float* W3 = (const float*)d_in[8];
    const float* b3 = (const float*)d_in[9];
    const float* W4 = (const float*)d_in[10];
    const float* b4 = (const float*)d_in[11];
    float* out = (float*)d_out;

    const int T    = 2048;
    const int rows = in_sizes[0] / 64;     // B*T
    const int B    = rows / T;             // 64

    char* ws = (char*)d_ws;
    const size_t xp_bytes = (size_t)rows * 512 * sizeof(__half);   // 128 MiB
    const size_t hs_bytes = (size_t)rows * 128 * sizeof(__half);   //  32 MiB

    __half *xp16, *hs16, *d1, *d2;
    const bool bigws = ws_size >= xp_bytes + hs_bytes;
    if (bigws) {
        xp16 = (__half*)ws;
        hs16 = (__half*)(ws + xp_bytes);
        d1   = (__half*)ws;
        d2   = (__half*)(ws + hs_bytes);
    } else {
        xp16 = nullptr;
        hs16 = (__half*)ws;
        d1   = (__half*)(ws + hs_bytes);
        d2   = (__half*)ws;
    }

    if (bigws) {
        k_xproj<<<2048, 512, 0, stream>>>(x, W, b, xp16, rows);
        k_lstm2<<<B, 512, 0, stream>>>(U, xp16, hs16, T);
    } else {
        k_lstm_fused<<<B, 512, 0, stream>>>(U, x, W, b, hs16, T);
    }
    k_fc128<false><<<1024, 512, 0, stream>>>(hs16, W1, b1, d1, rows);
    k_fc128<true ><<<1024, 512, 0, stream>>>(d1,  W2, b2, d2, rows);
    k_l34<<<1024, 512, 0, stream>>>(d2, W3, b3, W4, b4, out, rows);
}

// Round 3
// 1112.082 us; speedup vs baseline: 1.5691x; 1.3197x over previous
//
#include <hip/hip_runtime.h>
#include <hip/hip_fp16.h>
#include <cstdint>
#include <cstddef>

// ---------------------------------------------------------------------------
// helpers
// ---------------------------------------------------------------------------
typedef _Float16 hh2   __attribute__((ext_vector_type(2)));
typedef _Float16 f16x8 __attribute__((ext_vector_type(8)));
typedef float    f32x4 __attribute__((ext_vector_type(4)));

__device__ __forceinline__ float fdot2u(unsigned a, unsigned b, float c) {
#if __has_builtin(__builtin_amdgcn_fdot2)
    return __builtin_amdgcn_fdot2(__builtin_bit_cast(hh2, a),
                                  __builtin_bit_cast(hh2, b), c, false);
#else
    float r;
    asm("v_dot2_f32_f16 %0, %1, %2, %3" : "=v"(r) : "v"(a), "v"(b), "v"(c));
    return r;
#endif
}

__device__ __forceinline__ unsigned packh2f(float x, float y) {
    hh2 v; v.x = (_Float16)x; v.y = (_Float16)y;
    return __builtin_bit_cast(unsigned, v);
}

__device__ __forceinline__ float sigmoidf_fast(float x) {
    return __builtin_amdgcn_rcpf(1.f + __expf(-x));
}
__device__ __forceinline__ float tanhf_fast(float x) {
    float e = __expf(-2.f * fmaxf(x, -30.f));
    return (1.f - e) * __builtin_amdgcn_rcpf(1.f + e);
}

// raw barrier: drain LDS only, keep global loads in flight
#define BAR_LGKM() asm volatile("s_waitcnt lgkmcnt(0)\n\ts_barrier" ::: "memory")

// ---------------------------------------------------------------------------
// Kernel A: xpT = f16(x @ W + b) in chunked-transposed layout:
//   xpT[(row/8)][col][row%8]   (each [c8][col] cell = 8 halves = 16B)
// MFMA-based: 16 rows per chunk, A = x rows (f16, LDS swizzled), B = W frags.
// Grid = B*4 blocks (batch x T-quarter), 512 threads.
// ---------------------------------------------------------------------------
__global__ __launch_bounds__(512, 2)
void k_xprojT(const float* __restrict__ x, const float* __restrict__ W,
              const float* __restrict__ bias, __half* __restrict__ xpT,
              int B, int T)
{
    __shared__ unsigned short xst[2][16 * 64];  // [buf][row*64+k] halves, swizzled

    const int tid = threadIdx.x;
    const int w   = tid >> 6;
    const int l   = tid & 63;
    const int lj  = l & 15;
    const int hi  = l >> 4;
    const int bb  = blockIdx.x >> 2;
    const int q   = blockIdx.x & 3;

    // B-frags for W (K=64 -> 2 frags), 4 col-groups per wave
    f16x8 Wf[4][2];
    float bc[4];
#pragma unroll
    for (int cg = 0; cg < 4; ++cg) {
        const int col = cg * 128 + w * 16 + lj;
#pragma unroll
        for (int kk = 0; kk < 2; ++kk)
#pragma unroll
            for (int j = 0; j < 8; ++j)
                Wf[cg][kk][j] = (_Float16)W[(size_t)(kk*32 + hi*8 + j) * 512 + col];
        bc[cg] = bias[col];
    }

    const int nch = (T / 4) / 16;               // 32 chunks of 16 rows
    const size_t rowbase = (size_t)bb * T + (size_t)q * (T / 4);

    const int srow = tid >> 5;                  // 0..15
    const int scp  = tid & 31;                  // 0..31 (pairs of f32)

    float2 xn = *(const float2*)(x + (rowbase + srow) * 64 + scp * 2);

    for (int ch = 0; ch < nch; ++ch) {
        // pack + LDS write (swizzled row-major [16][64] halves)
        unsigned pk = packh2f(xn.x, xn.y);
        *(unsigned*)((char*)xst[ch & 1] +
            (((srow * 128 + scp * 4)) ^ ((srow & 7) << 4))) = pk;
        if (ch + 1 < nch)
            xn = *(const float2*)(x + (rowbase + (ch+1)*16 + srow) * 64 + scp * 2);
        BAR_LGKM();

        // A-frags: row = lj, k-slice per (kk,hi)
        f16x8 Axf[2];
#pragma unroll
        for (int kk = 0; kk < 2; ++kk)
            Axf[kk] = *(const f16x8*)((char*)xst[ch & 1] +
                ((lj * 128 + kk * 64 + hi * 16) ^ ((lj & 7) << 4)));

        const size_t c8base = (rowbase + (size_t)ch * 16) >> 3;
#pragma unroll
        for (int cg = 0; cg < 4; ++cg) {
            f32x4 C = {bc[cg], bc[cg], bc[cg], bc[cg]};
            C = __builtin_amdgcn_mfma_f32_16x16x32_f16(Axf[0], Wf[cg][0], C, 0, 0, 0);
            C = __builtin_amdgcn_mfma_f32_16x16x32_f16(Axf[1], Wf[cg][1], C, 0, 0, 0);
            const int col = cg * 128 + w * 16 + lj;
            uint2 u;
            u.x = packh2f(C[0], C[1]);
            u.y = packh2f(C[2], C[3]);
            // rows hi*4+r -> c8 = base + (hi>>1), slot = (hi&1)*4
            const size_t hidx = ((c8base + (hi >> 1)) * 512 + col) * 8 + (hi & 1) * 4;
            *(uint2*)((unsigned short*)xpT + hidx) = u;
        }
        BAR_LGKM();
    }
}

// ---------------------------------------------------------------------------
// Kernel B: MFMA LSTM + fused dense head. One block per batch element,
// 512 threads (8 waves). U resident in 64 VGPRs as B-frags.
// Per step: 4 ds_read_b128 (h frags) + 16 MFMA + in-lane activations +
// 1 ds_write_b16 + 1 raw barrier. xp prefetched 8-16 steps ahead into regs
// (chunked-transposed layout). h kept in a 16-slot LDS ring; hs stored to
// global in coalesced 2KB chunks. Head (d1..d4) runs as phase 2 per block.
// ---------------------------------------------------------------------------
__global__ __launch_bounds__(512, 2)
void k_lstm3(const float* __restrict__ U, const __half* __restrict__ xpT,
             __half* __restrict__ hs,
             const float* __restrict__ W1, const float* __restrict__ b1,
             const float* __restrict__ W2, const float* __restrict__ b2,
             const float* __restrict__ W3, const float* __restrict__ b3,
             const float* __restrict__ W4, const float* __restrict__ b4,
             float* __restrict__ out, int T)
{
    __shared__ unsigned short hring[16][128];     // h ring buffer (slot = t&15)
    __shared__ unsigned short hstage[16 * 128];   // head: staged hs rows (swz)
    __shared__ unsigned short d1buf[16 * 128];    // head: d1 (swz)
    __shared__ unsigned short d2buf[16 * 128];    // head: d2 (swz)
    __shared__ unsigned short d3buf[16 * 40];     // head: d3 (padded)

    const int tid = threadIdx.x;
    const int w   = tid >> 6;
    const int l   = tid & 63;
    const int lj  = l & 15;
    const int hi  = l >> 4;
    const int bb  = blockIdx.x;

    // ---- U B-frags (verified layout): Bf[g][kk][j] = U[kk*32+hi*8+j][col_g]
    f16x8 Bf[4][4];
#pragma unroll
    for (int g = 0; g < 4; ++g) {
        const int col = g * 128 + w * 16 + lj;
#pragma unroll
        for (int kk = 0; kk < 4; ++kk)
#pragma unroll
            for (int j = 0; j < 8; ++j)
                Bf[g][kk][j] = (_Float16)U[(size_t)(kk*32 + hi*8 + j) * 512 + col];
    }

    // zero initial-h slot (t=-1 -> slot 15)
    if (tid < 64) ((unsigned*)hring[15])[tid] = 0u;

    // xp prefetch: qA holds chunk 2k, qB chunk 2k+1 (8 steps each)
    const uint4* __restrict__ xb = (const uint4*)xpT;
    const size_t xrow = (size_t)bb * (T / 8) * 512;   // chunk row base
    int colg[4];
#pragma unroll
    for (int g = 0; g < 4; ++g) colg[g] = g * 128 + w * 16 + lj;

    uint4 qA[4], qB[4];
#pragma unroll
    for (int g = 0; g < 4; ++g) {
        qA[g] = xb[xrow + 0 * 512 + colg[g]];
        qB[g] = xb[xrow + 1 * 512 + colg[g]];
    }

    unsigned* __restrict__ hsw = (unsigned*)(hs + (size_t)bb * T * 128);
    float cst = 0.f;

    BAR_LGKM();

    const int nbody = T / 16;                   // 128
    for (int k = 0; k < nbody; ++k) {
#pragma unroll
        for (int p = 0; p < 16; ++p) {
            // coalesced hs stores (2KB every 8 steps)
            if (p == 2 && k > 0) {
                unsigned v = ((const unsigned*)hring[8])[tid];
                hsw[(size_t)(2*k - 1) * 512 + tid] = v;
            }
            if (p == 10) {
                unsigned v = ((const unsigned*)hring[0])[tid];
                hsw[(size_t)(2*k) * 512 + tid] = v;
            }
            // xp prefetch issues (register sets rotate; counted vmcnt)
            if (p == 8) {
#pragma unroll
                for (int g = 0; g < 4; ++g)
                    qA[g] = xb[xrow + (size_t)(2*k + 2) * 512 + colg[g]];
            }

            // A-frags from h(t-1) = ring slot (p+15)&15
            const unsigned short* hrow = &hring[(p + 15) & 15][0];
            f16x8 Af[4];
#pragma unroll
            for (int kk = 0; kk < 4; ++kk)
                Af[kk] = *(const f16x8*)(hrow + kk * 32 + hi * 8);

            // z from prefetched xp
            float zf[4];
#pragma unroll
            for (int g = 0; g < 4; ++g) {
                const uint4 qq = (p < 8) ? qA[g] : qB[g];
                const int wsel = (p & 7) >> 1;
                unsigned uw = (wsel == 0) ? qq.x : (wsel == 1) ? qq.y
                            : (wsel == 2) ? qq.z : qq.w;
                __half2 hh = __builtin_bit_cast(__half2, uw);
                zf[g] = __half2float((p & 1) ? __high2half(hh) : __low2half(hh));
            }

            f32x4 Cf[4];
#pragma unroll
            for (int g = 0; g < 4; ++g) {
                f32x4 ci = {zf[g], zf[g], zf[g], zf[g]};
                Cf[g] = ci;
            }
#pragma unroll
            for (int kk = 0; kk < 4; ++kk)
#pragma unroll
                for (int g = 0; g < 4; ++g)
                    Cf[g] = __builtin_amdgcn_mfma_f32_16x16x32_f16(Af[kk], Bf[g][kk], Cf[g], 0, 0, 0);

            // gates (all lanes redundant across hi groups; identical values)
            float iv = sigmoidf_fast(Cf[0][0]);
            float fv = sigmoidf_fast(Cf[1][0]);
            float gv = tanhf_fast(Cf[2][0]);
            float ov = sigmoidf_fast(Cf[3][0]);
            cst = fmaf(fv, cst, iv * gv);
            float h = ov * tanhf_fast(cst);

            if (l < 16)
                hring[p][w * 16 + lj] = __half_as_ushort(__float2half(h));

            if (p == 15) {
#pragma unroll
                for (int g = 0; g < 4; ++g)
                    qB[g] = xb[xrow + (size_t)(2*k + 3) * 512 + colg[g]];
            }
            BAR_LGKM();
        }
    }
    // tail hs store (chunk 2*nbody-1 = rows T-8..T)
    {
        unsigned v = ((const unsigned*)hring[8])[tid];
        hsw[(size_t)(T/8 - 1) * 512 + tid] = v;
    }
    asm volatile("s_waitcnt vmcnt(0)" ::: "memory");
    __syncthreads();

    // =======================  PHASE 2: dense head  =========================
    // d1 = hs@W1+b1 ; d2 = relu(d1@W2+b2) ; d3 = relu(d2@W3+b3) ;
    // out = sigmoid(d3@W4+b4)
    const int col1 = w * 16 + lj;          // 0..127
    const int col3 = (w & 1) * 16 + lj;    // 0..31 (waves 0,1 authoritative)

    f16x8 W1f[4], W2f[4], W3f[4];
    float b1c, b2c, b3c;
#pragma unroll
    for (int kk = 0; kk < 4; ++kk)
#pragma unroll
        for (int j = 0; j < 8; ++j) {
            W1f[kk][j] = (_Float16)W1[(size_t)(kk*32 + hi*8 + j) * 128 + col1];
            W2f[kk][j] = (_Float16)W2[(size_t)(kk*32 + hi*8 + j) * 128 + col1];
            W3f[kk][j] = (_Float16)W3[(size_t)(kk*32 + hi*8 + j) * 32 + col3];
        }
    b1c = b1[col1];
    b2c = b2[col1];
    b3c = b3[col3];
    unsigned w4p[16];
#pragma unroll
    for (int k2 = 0; k2 < 16; ++k2)
        w4p[k2] = packh2f(W4[2*k2], W4[2*k2 + 1]);
    const float b4v = b4[0];

    const __half* __restrict__ hsb = hs + (size_t)bb * T * 128;
    const int srow = tid >> 5;      // 0..15
    const int scp  = tid & 31;      // 0..31 (4-half groups)

    for (int ch = 0; ch < T / 16; ++ch) {
        const int t0 = ch * 16;
        // stage 16 rows of hs (swizzled)
        uint2 hv = *(const uint2*)(hsb + (size_t)(t0 + srow) * 128 + scp * 4);
        *(uint2*)((char*)hstage + ((srow * 256 + scp * 8) ^ ((srow & 7) << 4))) = hv;
        __syncthreads();

        // ---- layer 1 (linear)
        f16x8 A[4];
#pragma unroll
        for (int kk = 0; kk < 4; ++kk)
            A[kk] = *(const f16x8*)((char*)hstage +
                ((lj * 256 + kk * 64 + hi * 16) ^ ((lj & 7) << 4)));
        f32x4 C1 = {b1c, b1c, b1c, b1c};
#pragma unroll
        for (int kk = 0; kk < 4; ++kk)
            C1 = __builtin_amdgcn_mfma_f32_16x16x32_f16(A[kk], W1f[kk], C1, 0, 0, 0);
#pragma unroll
        for (int r = 0; r < 4; ++r) {
            const int row = hi * 4 + r;
            *(unsigned short*)((char*)d1buf + ((row * 256 + col1 * 2) ^ ((row & 7) << 4))) =
                __half_as_ushort(__float2half(C1[r]));
        }
        __syncthreads();

        // ---- layer 2 (relu)
#pragma unroll
        for (int kk = 0; kk < 4; ++kk)
            A[kk] = *(const f16x8*)((char*)d1buf +
                ((lj * 256 + kk * 64 + hi * 16) ^ ((lj & 7) << 4)));
        f32x4 C2 = {b2c, b2c, b2c, b2c};
#pragma unroll
        for (int kk = 0; kk < 4; ++kk)
            C2 = __builtin_amdgcn_mfma_f32_16x16x32_f16(A[kk], W2f[kk], C2, 0, 0, 0);
#pragma unroll
        for (int r = 0; r < 4; ++r) {
            const int row = hi * 4 + r;
            *(unsigned short*)((char*)d2buf + ((row * 256 + col1 * 2) ^ ((row & 7) << 4))) =
                __half_as_ushort(__float2half(fmaxf(C2[r], 0.f)));
        }
        __syncthreads();

        // ---- layer 3 (relu, 32 cols; waves 0-1 write)
#pragma unroll
        for (int kk = 0; kk < 4; ++kk)
            A[kk] = *(const f16x8*)((char*)d2buf +
                ((lj * 256 + kk * 64 + hi * 16) ^ ((lj & 7) << 4)));
        f32x4 C3 = {b3c, b3c, b3c, b3c};
#pragma unroll
        for (int kk = 0; kk < 4; ++kk)
            C3 = __builtin_amdgcn_mfma_f32_16x16x32_f16(A[kk], W3f[kk], C3, 0, 0, 0);
        if (w < 2) {
#pragma unroll
            for (int r = 0; r < 4; ++r) {
                const int row = hi * 4 + r;
                d3buf[row * 40 + col3] =
                    __half_as_ushort(__float2half(fmaxf(C3[r], 0.f)));
            }
        }
        __syncthreads();

        // ---- layer 4 (sigmoid) by wave 0 lanes 0-15
        if (w == 0 && l < 16) {
            const unsigned short* dr = &d3buf[l * 40];
            float s0 = b4v, s1 = 0.f;
#pragma unroll
            for (int qq = 0; qq < 4; ++qq) {
                uint4 v = *(const uint4*)(dr + qq * 8);
                s0 = fdot2u(v.x, w4p[qq*4 + 0], s0);
                s1 = fdot2u(v.y, w4p[qq*4 + 1], s1);
                s0 = fdot2u(v.z, w4p[qq*4 + 2], s0);
                s1 = fdot2u(v.w, w4p[qq*4 + 3], s1);
            }
            out[(size_t)bb * T + t0 + l] = sigmoidf_fast(s0 + s1);
        }
        __syncthreads();
    }
}

// ---------------------------------------------------------------------------
// Fallback path (small workspace): round-1 fused dot2 LSTM + dot2 head.
// ---------------------------------------------------------------------------
__global__ __launch_bounds__(512)
void k_lstm_fused(const float* __restrict__ U, const float* __restrict__ x,
                  const float* __restrict__ W, const float* __restrict__ bias,
                  __half* __restrict__ hs, int T)
{
    __shared__ __align__(16) unsigned hbuf[64];
    __shared__ float act[512];
    __shared__ __align__(16) unsigned xrow[32];

    const int g    = threadIdx.x;
    const int bb   = blockIdx.x;
    const int j    = g & 127;
    const int gate = g >> 7;

    unsigned ucol[64];
#pragma unroll
    for (int k2 = 0; k2 < 64; ++k2)
        ucol[k2] = packh2f(U[(2*k2)*512 + g], U[(2*k2+1)*512 + g]);
    unsigned wcol[32];
#pragma unroll
    for (int k2 = 0; k2 < 32; ++k2)
        wcol[k2] = packh2f(W[(2*k2)*512 + g], W[(2*k2+1)*512 + g]);
    const float bg = bias[g];
    const float2* __restrict__ xb2 = (const float2*)(x + (size_t)bb * T * 64);
    if (g < 32) { float2 x0 = xb2[g]; xrow[g] = packh2f(x0.x, x0.y); }
    if (g < 64) hbuf[g] = 0u;
    float c = 0.f;
    __half* __restrict__ hsb = hs + (size_t)bb * T * 128;
    __syncthreads();

    for (int t = 0; t < T; ++t) {
        float2 xn = make_float2(0.f, 0.f);
        if (g < 32 && t + 1 < T) xn = xb2[(size_t)(t + 1) * 32 + g];
        float a0 = bg, a1 = 0.f, a2 = 0.f, a3 = 0.f;
        const uint4* hr = (const uint4*)hbuf;
#pragma unroll
        for (int k8 = 0; k8 < 16; ++k8) {
            uint4 v = hr[k8];
            a0 = fdot2u(v.x, ucol[4*k8+0], a0);
            a1 = fdot2u(v.y, ucol[4*k8+1], a1);
            a2 = fdot2u(v.z, ucol[4*k8+2], a2);
            a3 = fdot2u(v.w, ucol[4*k8+3], a3);
        }
        const uint4* xr = (const uint4*)xrow;
#pragma unroll
        for (int k8 = 0; k8 < 8; ++k8) {
            uint4 v = xr[k8];
            a0 = fdot2u(v.x, wcol[4*k8+0], a0);
            a1 = fdot2u(v.y, wcol[4*k8+1], a1);
            a2 = fdot2u(v.z, wcol[4*k8+2], a2);
            a3 = fdot2u(v.w, wcol[4*k8+3], a3);
        }
        float z = (a0 + a1) + (a2 + a3);
        float a = (gate == 2) ? tanhf_fast(z) : sigmoidf_fast(z);
        act[g] = a;
        __syncthreads();
        float iv = act[j], fv = act[j + 128], gv = act[j + 256], ov = act[j + 384];
        c = fmaf(fv, c, iv * gv);
        float h = ov * tanhf_fast(c);
        if (gate == 0) {
            ((unsigned short*)hbuf)[j] = __half_as_ushort(__float2half(h));
            hsb[(size_t)t * 128 + j] = __float2half(h);
        }
        if (g < 32 && t + 1 < T) xrow[g] = packh2f(xn.x, xn.y);
        __syncthreads();
    }
}

template<bool RELU>
__global__ __launch_bounds__(512)
void k_fc128(const __half* __restrict__ in16, const float* __restrict__ Wg,
             const float* __restrict__ bias, __half* __restrict__ out16, int rows)
{
    __shared__ __align__(16) unsigned rowbuf[4 * 64];
    const int tid = threadIdx.x;
    const int n   = tid & 127;
    const int rs  = tid >> 7;
    unsigned wcol[64];
#pragma unroll
    for (int k2 = 0; k2 < 64; ++k2)
        wcol[k2] = packh2f(Wg[(2*k2)*128 + n], Wg[(2*k2+1)*128 + n]);
    const float bn = bias[n];
    for (int row0 = blockIdx.x * 4; row0 < rows; row0 += gridDim.x * 4) {
        if (tid < 256)
            rowbuf[tid] = ((const unsigned*)(in16 + (size_t)row0 * 128))[tid];
        __syncthreads();
        float a0 = bn, a1 = 0.f, a2 = 0.f, a3 = 0.f;
        const uint4* hr = (const uint4*)(rowbuf + rs * 64);
#pragma unroll
        for (int k8 = 0; k8 < 16; ++k8) {
            uint4 v = hr[k8];
            a0 = fdot2u(v.x, wcol[4*k8+0], a0);
            a1 = fdot2u(v.y, wcol[4*k8+1], a1);
            a2 = fdot2u(v.z, wcol[4*k8+2], a2);
            a3 = fdot2u(v.w, wcol[4*k8+3], a3);
        }
        float a = (a0 + a1) + (a2 + a3);
        if (RELU) a = fmaxf(a, 0.f);
        out16[(size_t)(row0 + rs) * 128 + n] = __float2half(a);
        __syncthreads();
    }
}

__global__ __launch_bounds__(512)
void k_l34(const __half* __restrict__ in16, const float* __restrict__ W3,
           const float* __restrict__ b3, const float* __restrict__ W4,
           const float* __restrict__ b4, float* __restrict__ out, int rows)
{
    __shared__ __align__(16) unsigned rowbuf[16 * 64];
    __shared__ __align__(16) unsigned short d3s[16 * 32];
    const int tid = threadIdx.x;
    const int n   = tid & 31;
    const int rs  = tid >> 5;
    unsigned w3col[64];
#pragma unroll
    for (int k2 = 0; k2 < 64; ++k2)
        w3col[k2] = packh2f(W3[(2*k2)*32 + n], W3[(2*k2+1)*32 + n]);
    unsigned w4p[16];
#pragma unroll
    for (int k2 = 0; k2 < 16; ++k2)
        w4p[k2] = packh2f(W4[2*k2], W4[2*k2+1]);
    const float b3n = b3[n], b4v = b4[0];
    for (int row0 = blockIdx.x * 16; row0 < rows; row0 += gridDim.x * 16) {
        rowbuf[tid]       = ((const unsigned*)(in16 + (size_t)row0 * 128))[tid];
        rowbuf[tid + 512] = ((const unsigned*)(in16 + (size_t)row0 * 128))[tid + 512];
        __syncthreads();
        float a0 = b3n, a1 = 0.f, a2 = 0.f, a3 = 0.f;
        const uint4* hr = (const uint4*)(rowbuf + rs * 64);
#pragma unroll
        for (int k8 = 0; k8 < 16; ++k8) {
            uint4 v = hr[k8];
            a0 = fdot2u(v.x, w3col[4*k8+0], a0);
            a1 = fdot2u(v.y, w3col[4*k8+1], a1);
            a2 = fdot2u(v.z, w3col[4*k8+2], a2);
            a3 = fdot2u(v.w, w3col[4*k8+3], a3);
        }
        float a = fmaxf((a0 + a1) + (a2 + a3), 0.f);
        d3s[rs * 32 + n] = __half_as_ushort(__float2half(a));
        __syncthreads();
        if (tid < 16) {
            const uint4* dp = (const uint4*)(d3s + tid * 32);
            float s0 = b4v, s1 = 0.f;
#pragma unroll
            for (int qq = 0; qq < 4; ++qq) {
                uint4 v = dp[qq];
                s0 = fdot2u(v.x, w4p[4*qq+0], s0);
                s1 = fdot2u(v.y, w4p[4*qq+1], s1);
                s0 = fdot2u(v.z, w4p[4*qq+2], s0);
                s1 = fdot2u(v.w, w4p[4*qq+3], s1);
            }
            out[row0 + tid] = sigmoidf_fast(s0 + s1);
        }
        __syncthreads();
    }
}

// ---------------------------------------------------------------------------
extern "C" void kernel_launch(void* const* d_in, const int* in_sizes, int n_in,
                              void* d_out, int out_size, void* d_ws, size_t ws_size,
                              hipStream_t stream)
{
    const float* x  = (const float*)d_in[0];
    const float* W  = (const float*)d_in[1];
    const float* U  = (const float*)d_in[2];
    const float* b  = (const float*)d_in[3];
    const float* W1 = (const float*)d_in[4];
    const float* b1 = (const float*)d_in[5];
    const float* W2 = (const float*)d_in[6];
    const float* b2 = (const float*)d_in[7];
    const float* W3 = (const float*)d_in[8];
    const float* b3 = (const float*)d_in[9];
    const float* W4 = (const float*)d_in[10];
    const float* b4 = (const float*)d_in[11];
    float* out = (float*)d_out;

    const int T    = 2048;
    const int rows = in_sizes[0] / 64;     // B*T
    const int B    = rows / T;             // 64

    char* ws = (char*)d_ws;
    const size_t xp_bytes = (size_t)rows * 512 * sizeof(__half);   // 128 MiB
    const size_t hs_bytes = (size_t)rows * 128 * sizeof(__half);   //  32 MiB

    if (ws_size >= xp_bytes + hs_bytes) {
        __half* xpT  = (__half*)ws;
        __half* hs16 = (__half*)(ws + xp_bytes);
        k_xprojT<<<B * 4, 512, 0, stream>>>(x, W, b, xpT, B, T);
        k_lstm3<<<B, 512, 0, stream>>>(U, xpT, hs16,
                                       W1, b1, W2, b2, W3, b3, W4, b4, out, T);
    } else {
        __half* hs16 = (__half*)ws;
        __half* d1   = (__half*)(ws + hs_bytes);
        __half* d2   = (__half*)ws;   // alias hs (dead after fc1)
        k_lstm_fused<<<B, 512, 0, stream>>>(U, x, W, b, hs16, T);
        k_fc128<false><<<1024, 512, 0, stream>>>(hs16, W1, b1, d1, rows);
        k_fc128<true ><<<1024, 512, 0, stream>>>(d1,  W2, b2, d2, rows);
        k_l34<<<1024, 512, 0, stream>>>(d2, W3, b3, W4, b4, out, rows);
    }
}

// Round 4
// 1029.469 us; speedup vs baseline: 1.6950x; 1.0802x over previous
//
#include <hip/hip_runtime.h>
#include <hip/hip_fp16.h>
#include <cstdint>
#include <cstddef>

// ---------------------------------------------------------------------------
// helpers
// ---------------------------------------------------------------------------
typedef _Float16 hh2   __attribute__((ext_vector_type(2)));
typedef _Float16 f16x8 __attribute__((ext_vector_type(8)));
typedef float    f32x4 __attribute__((ext_vector_type(4)));

__device__ __forceinline__ float fdot2u(unsigned a, unsigned b, float c) {
#if __has_builtin(__builtin_amdgcn_fdot2)
    return __builtin_amdgcn_fdot2(__builtin_bit_cast(hh2, a),
                                  __builtin_bit_cast(hh2, b), c, false);
#else
    float r;
    asm("v_dot2_f32_f16 %0, %1, %2, %3" : "=v"(r) : "v"(a), "v"(b), "v"(c));
    return r;
#endif
}

__device__ __forceinline__ unsigned packh2f(float x, float y) {
    hh2 v; v.x = (_Float16)x; v.y = (_Float16)y;
    return __builtin_bit_cast(unsigned, v);
}

__device__ __forceinline__ float sigmoidf_fast(float x) {
    return __builtin_amdgcn_rcpf(1.f + __expf(-x));
}
__device__ __forceinline__ float tanhf_fast(float x) {
    float e = __expf(-2.f * fmaxf(x, -30.f));
    return (1.f - e) * __builtin_amdgcn_rcpf(1.f + e);
}

// raw barrier: drain LDS only, keep global loads in flight
#define BAR_LGKM() asm volatile("s_waitcnt lgkmcnt(0)\n\ts_barrier" ::: "memory")

// ---------------------------------------------------------------------------
// Kernel A: xpT = f16(x @ W + b) in chunked-transposed layout:
//   xpT[(row/8)][col][row%8]   (each [c8][col] cell = 8 halves = 16B)
// ---------------------------------------------------------------------------
__global__ __launch_bounds__(512, 2)
void k_xprojT(const float* __restrict__ x, const float* __restrict__ W,
              const float* __restrict__ bias, __half* __restrict__ xpT,
              int B, int T)
{
    __shared__ unsigned short xst[2][16 * 64];  // [buf][row*64+k] halves, swizzled

    const int tid = threadIdx.x;
    const int w   = tid >> 6;
    const int l   = tid & 63;
    const int lj  = l & 15;
    const int hi  = l >> 4;
    const int bb  = blockIdx.x >> 2;
    const int q   = blockIdx.x & 3;

    f16x8 Wf[4][2];
    float bc[4];
#pragma unroll
    for (int cg = 0; cg < 4; ++cg) {
        const int col = cg * 128 + w * 16 + lj;
#pragma unroll
        for (int kk = 0; kk < 2; ++kk)
#pragma unroll
            for (int j = 0; j < 8; ++j)
                Wf[cg][kk][j] = (_Float16)W[(size_t)(kk*32 + hi*8 + j) * 512 + col];
        bc[cg] = bias[col];
    }

    const int nch = (T / 4) / 16;
    const size_t rowbase = (size_t)bb * T + (size_t)q * (T / 4);

    const int srow = tid >> 5;
    const int scp  = tid & 31;

    float2 xn = *(const float2*)(x + (rowbase + srow) * 64 + scp * 2);

    for (int ch = 0; ch < nch; ++ch) {
        unsigned pk = packh2f(xn.x, xn.y);
        *(unsigned*)((char*)xst[ch & 1] +
            (((srow * 128 + scp * 4)) ^ ((srow & 7) << 4))) = pk;
        if (ch + 1 < nch)
            xn = *(const float2*)(x + (rowbase + (ch+1)*16 + srow) * 64 + scp * 2);
        BAR_LGKM();

        f16x8 Axf[2];
#pragma unroll
        for (int kk = 0; kk < 2; ++kk)
            Axf[kk] = *(const f16x8*)((char*)xst[ch & 1] +
                ((lj * 128 + kk * 64 + hi * 16) ^ ((lj & 7) << 4)));

        const size_t c8base = (rowbase + (size_t)ch * 16) >> 3;
#pragma unroll
        for (int cg = 0; cg < 4; ++cg) {
            f32x4 C = {bc[cg], bc[cg], bc[cg], bc[cg]};
            C = __builtin_amdgcn_mfma_f32_16x16x32_f16(Axf[0], Wf[cg][0], C, 0, 0, 0);
            C = __builtin_amdgcn_mfma_f32_16x16x32_f16(Axf[1], Wf[cg][1], C, 0, 0, 0);
            const int col = cg * 128 + w * 16 + lj;
            uint2 u;
            u.x = packh2f(C[0], C[1]);
            u.y = packh2f(C[2], C[3]);
            const size_t hidx = ((c8base + (hi >> 1)) * 512 + col) * 8 + (hi & 1) * 4;
            *(uint2*)((unsigned short*)xpT + hidx) = u;
        }
        BAR_LGKM();
    }
}

// ---------------------------------------------------------------------------
// Kernel B: MFMA LSTM (lean-VALU) + fused dense head.
// Per step per wave: 4 ds_read_b128 + 16 MFMA + ~40 VALU + 1 barrier.
// Persistent Cf: only element 0 is re-seeded with z each step (elements 1-3
// accumulate bounded garbage, never read). Waves 0-3 run at prio 1 so each
// SIMD's wave pair staggers: one wave's VALU phase overlaps the other's MFMAs.
// ---------------------------------------------------------------------------
__global__ __launch_bounds__(512, 2)
void k_lstm4(const float* __restrict__ U, const __half* __restrict__ xpT,
             __half* __restrict__ hs,
             const float* __restrict__ W1, const float* __restrict__ b1,
             const float* __restrict__ W2, const float* __restrict__ b2,
             const float* __restrict__ W3, const float* __restrict__ b3,
             const float* __restrict__ W4, const float* __restrict__ b4,
             float* __restrict__ out, int T)
{
    __shared__ unsigned short hring[16][128];
    __shared__ unsigned short hstage[16 * 128];
    __shared__ unsigned short d1buf[16 * 128];
    __shared__ unsigned short d2buf[16 * 128];
    __shared__ unsigned short d3buf[16 * 40];

    const int tid = threadIdx.x;
    const int w   = tid >> 6;
    const int l   = tid & 63;
    const int lj  = l & 15;
    const int hi  = l >> 4;
    const int bb  = blockIdx.x;

    f16x8 Bf[4][4];
#pragma unroll
    for (int g = 0; g < 4; ++g) {
        const int col = g * 128 + w * 16 + lj;
#pragma unroll
        for (int kk = 0; kk < 4; ++kk)
#pragma unroll
            for (int j = 0; j < 8; ++j)
                Bf[g][kk][j] = (_Float16)U[(size_t)(kk*32 + hi*8 + j) * 512 + col];
    }

    if (tid < 64) ((unsigned*)hring[15])[tid] = 0u;

    const uint4* __restrict__ xb = (const uint4*)xpT;
    const size_t xrow = (size_t)bb * (T / 8) * 512;
    int colg[4];
#pragma unroll
    for (int g = 0; g < 4; ++g) colg[g] = g * 128 + w * 16 + lj;

    uint4 qA[4], qB[4];
#pragma unroll
    for (int g = 0; g < 4; ++g) {
        qA[g] = xb[xrow + 0 * 512 + colg[g]];
        qB[g] = xb[xrow + 1 * 512 + colg[g]];
    }

    unsigned* __restrict__ hsw = (unsigned*)(hs + (size_t)bb * T * 128);
    float cst = 0.f;

    // stagger: half the waves get elevated priority for the whole loop
    if (w < 4) __builtin_amdgcn_s_setprio(1);

    // persistent accumulators; elem 0 reseeded per step, elems 1-3 garbage
    f32x4 Cf[4] = {{0,0,0,0},{0,0,0,0},{0,0,0,0},{0,0,0,0}};

    BAR_LGKM();

    const int nbody = T / 16;
    for (int k = 0; k < nbody; ++k) {
#pragma unroll
        for (int p = 0; p < 16; ++p) {
            if (p == 2 && k > 0) {
                unsigned v = ((const unsigned*)hring[8])[tid];
                hsw[(size_t)(2*k - 1) * 512 + tid] = v;
            }
            if (p == 10) {
                unsigned v = ((const unsigned*)hring[0])[tid];
                hsw[(size_t)(2*k) * 512 + tid] = v;
            }
            if (p == 8) {
#pragma unroll
                for (int g = 0; g < 4; ++g)
                    qA[g] = xb[xrow + (size_t)(2*k + 2) * 512 + colg[g]];
            }

            const unsigned short* hrow = &hring[(p + 15) & 15][0];
            f16x8 Af[4];
#pragma unroll
            for (int kk = 0; kk < 4; ++kk)
                Af[kk] = *(const f16x8*)(hrow + kk * 32 + hi * 8);

            // seed elem 0 of each accumulator with z (= xp value)
#pragma unroll
            for (int g = 0; g < 4; ++g) {
                const uint4 qq = (p < 8) ? qA[g] : qB[g];
                const int wsel = (p & 7) >> 1;
                unsigned uw = (wsel == 0) ? qq.x : (wsel == 1) ? qq.y
                            : (wsel == 2) ? qq.z : qq.w;
                __half2 hh = __builtin_bit_cast(__half2, uw);
                Cf[g][0] = __half2float((p & 1) ? __high2half(hh) : __low2half(hh));
            }
#pragma unroll
            for (int kk = 0; kk < 4; ++kk)
#pragma unroll
                for (int g = 0; g < 4; ++g)
                    Cf[g] = __builtin_amdgcn_mfma_f32_16x16x32_f16(Af[kk], Bf[g][kk], Cf[g], 0, 0, 0);

            float iv = sigmoidf_fast(Cf[0][0]);
            float fv = sigmoidf_fast(Cf[1][0]);
            float gv = tanhf_fast(Cf[2][0]);
            float ov = sigmoidf_fast(Cf[3][0]);
            cst = fmaf(fv, cst, iv * gv);
            float h = ov * tanhf_fast(cst);

            if (l < 16)
                hring[p][w * 16 + lj] = __half_as_ushort(__float2half(h));

            if (p == 15) {
#pragma unroll
                for (int g = 0; g < 4; ++g)
                    qB[g] = xb[xrow + (size_t)(2*k + 3) * 512 + colg[g]];
            }
            BAR_LGKM();
        }
    }
    {
        unsigned v = ((const unsigned*)hring[8])[tid];
        hsw[(size_t)(T/8 - 1) * 512 + tid] = v;
    }
    __builtin_amdgcn_s_setprio(0);
    asm volatile("s_waitcnt vmcnt(0)" ::: "memory");
    __syncthreads();

    // =======================  PHASE 2: dense head  =========================
    const int col1 = w * 16 + lj;
    const int col3 = (w & 1) * 16 + lj;

    f16x8 W1f[4], W2f[4], W3f[4];
    float b1c, b2c, b3c;
#pragma unroll
    for (int kk = 0; kk < 4; ++kk)
#pragma unroll
        for (int j = 0; j < 8; ++j) {
            W1f[kk][j] = (_Float16)W1[(size_t)(kk*32 + hi*8 + j) * 128 + col1];
            W2f[kk][j] = (_Float16)W2[(size_t)(kk*32 + hi*8 + j) * 128 + col1];
            W3f[kk][j] = (_Float16)W3[(size_t)(kk*32 + hi*8 + j) * 32 + col3];
        }
    b1c = b1[col1];
    b2c = b2[col1];
    b3c = b3[col3];
    unsigned w4p[16];
#pragma unroll
    for (int k2 = 0; k2 < 16; ++k2)
        w4p[k2] = packh2f(W4[2*k2], W4[2*k2 + 1]);
    const float b4v = b4[0];

    const __half* __restrict__ hsb = hs + (size_t)bb * T * 128;
    const int srow = tid >> 5;
    const int scp  = tid & 31;

    for (int ch = 0; ch < T / 16; ++ch) {
        const int t0 = ch * 16;
        uint2 hv = *(const uint2*)(hsb + (size_t)(t0 + srow) * 128 + scp * 4);
        *(uint2*)((char*)hstage + ((srow * 256 + scp * 8) ^ ((srow & 7) << 4))) = hv;
        __syncthreads();

        f16x8 A[4];
#pragma unroll
        for (int kk = 0; kk < 4; ++kk)
            A[kk] = *(const f16x8*)((char*)hstage +
                ((lj * 256 + kk * 64 + hi * 16) ^ ((lj & 7) << 4)));
        f32x4 C1 = {b1c, b1c, b1c, b1c};
#pragma unroll
        for (int kk = 0; kk < 4; ++kk)
            C1 = __builtin_amdgcn_mfma_f32_16x16x32_f16(A[kk], W1f[kk], C1, 0, 0, 0);
#pragma unroll
        for (int r = 0; r < 4; ++r) {
            const int row = hi * 4 + r;
            *(unsigned short*)((char*)d1buf + ((row * 256 + col1 * 2) ^ ((row & 7) << 4))) =
                __half_as_ushort(__float2half(C1[r]));
        }
        __syncthreads();

#pragma unroll
        for (int kk = 0; kk < 4; ++kk)
            A[kk] = *(const f16x8*)((char*)d1buf +
                ((lj * 256 + kk * 64 + hi * 16) ^ ((lj & 7) << 4)));
        f32x4 C2 = {b2c, b2c, b2c, b2c};
#pragma unroll
        for (int kk = 0; kk < 4; ++kk)
            C2 = __builtin_amdgcn_mfma_f32_16x16x32_f16(A[kk], W2f[kk], C2, 0, 0, 0);
#pragma unroll
        for (int r = 0; r < 4; ++r) {
            const int row = hi * 4 + r;
            *(unsigned short*)((char*)d2buf + ((row * 256 + col1 * 2) ^ ((row & 7) << 4))) =
                __half_as_ushort(__float2half(fmaxf(C2[r], 0.f)));
        }
        __syncthreads();

#pragma unroll
        for (int kk = 0; kk < 4; ++kk)
            A[kk] = *(const f16x8*)((char*)d2buf +
                ((lj * 256 + kk * 64 + hi * 16) ^ ((lj & 7) << 4)));
        f32x4 C3 = {b3c, b3c, b3c, b3c};
#pragma unroll
        for (int kk = 0; kk < 4; ++kk)
            C3 = __builtin_amdgcn_mfma_f32_16x16x32_f16(A[kk], W3f[kk], C3, 0, 0, 0);
        if (w < 2) {
#pragma unroll
            for (int r = 0; r < 4; ++r) {
                const int row = hi * 4 + r;
                d3buf[row * 40 + col3] =
                    __half_as_ushort(__float2half(fmaxf(C3[r], 0.f)));
            }
        }
        __syncthreads();

        if (w == 0 && l < 16) {
            const unsigned short* dr = &d3buf[l * 40];
            float s0 = b4v, s1 = 0.f;
#pragma unroll
            for (int qq = 0; qq < 4; ++qq) {
                uint4 v = *(const uint4*)(dr + qq * 8);
                s0 = fdot2u(v.x, w4p[qq*4 + 0], s0);
                s1 = fdot2u(v.y, w4p[qq*4 + 1], s1);
                s0 = fdot2u(v.z, w4p[qq*4 + 2], s0);
                s1 = fdot2u(v.w, w4p[qq*4 + 3], s1);
            }
            out[(size_t)bb * T + t0 + l] = sigmoidf_fast(s0 + s1);
        }
        __syncthreads();
    }
}

// ---------------------------------------------------------------------------
// Fallback path (small workspace): round-1 fused dot2 LSTM + dot2 head.
// ---------------------------------------------------------------------------
__global__ __launch_bounds__(512)
void k_lstm_fused(const float* __restrict__ U, const float* __restrict__ x,
                  const float* __restrict__ W, const float* __restrict__ bias,
                  __half* __restrict__ hs, int T)
{
    __shared__ __align__(16) unsigned hbuf[64];
    __shared__ float act[512];
    __shared__ __align__(16) unsigned xrow[32];

    const int g    = threadIdx.x;
    const int bb   = blockIdx.x;
    const int j    = g & 127;
    const int gate = g >> 7;

    unsigned ucol[64];
#pragma unroll
    for (int k2 = 0; k2 < 64; ++k2)
        ucol[k2] = packh2f(U[(2*k2)*512 + g], U[(2*k2+1)*512 + g]);
    unsigned wcol[32];
#pragma unroll
    for (int k2 = 0; k2 < 32; ++k2)
        wcol[k2] = packh2f(W[(2*k2)*512 + g], W[(2*k2+1)*512 + g]);
    const float bg = bias[g];
    const float2* __restrict__ xb2 = (const float2*)(x + (size_t)bb * T * 64);
    if (g < 32) { float2 x0 = xb2[g]; xrow[g] = packh2f(x0.x, x0.y); }
    if (g < 64) hbuf[g] = 0u;
    float c = 0.f;
    __half* __restrict__ hsb = hs + (size_t)bb * T * 128;
    __syncthreads();

    for (int t = 0; t < T; ++t) {
        float2 xn = make_float2(0.f, 0.f);
        if (g < 32 && t + 1 < T) xn = xb2[(size_t)(t + 1) * 32 + g];
        float a0 = bg, a1 = 0.f, a2 = 0.f, a3 = 0.f;
        const uint4* hr = (const uint4*)hbuf;
#pragma unroll
        for (int k8 = 0; k8 < 16; ++k8) {
            uint4 v = hr[k8];
            a0 = fdot2u(v.x, ucol[4*k8+0], a0);
            a1 = fdot2u(v.y, ucol[4*k8+1], a1);
            a2 = fdot2u(v.z, ucol[4*k8+2], a2);
            a3 = fdot2u(v.w, ucol[4*k8+3], a3);
        }
        const uint4* xr = (const uint4*)xrow;
#pragma unroll
        for (int k8 = 0; k8 < 8; ++k8) {
            uint4 v = xr[k8];
            a0 = fdot2u(v.x, wcol[4*k8+0], a0);
            a1 = fdot2u(v.y, wcol[4*k8+1], a1);
            a2 = fdot2u(v.z, wcol[4*k8+2], a2);
            a3 = fdot2u(v.w, wcol[4*k8+3], a3);
        }
        float z = (a0 + a1) + (a2 + a3);
        float a = (gate == 2) ? tanhf_fast(z) : sigmoidf_fast(z);
        act[g] = a;
        __syncthreads();
        float iv = act[j], fv = act[j + 128], gv = act[j + 256], ov = act[j + 384];
        c = fmaf(fv, c, iv * gv);
        float h = ov * tanhf_fast(c);
        if (gate == 0) {
            ((unsigned short*)hbuf)[j] = __half_as_ushort(__float2half(h));
            hsb[(size_t)t * 128 + j] = __float2half(h);
        }
        if (g < 32 && t + 1 < T) xrow[g] = packh2f(xn.x, xn.y);
        __syncthreads();
    }
}

template<bool RELU>
__global__ __launch_bounds__(512)
void k_fc128(const __half* __restrict__ in16, const float* __restrict__ Wg,
             const float* __restrict__ bias, __half* __restrict__ out16, int rows)
{
    __shared__ __align__(16) unsigned rowbuf[4 * 64];
    const int tid = threadIdx.x;
    const int n   = tid & 127;
    const int rs  = tid >> 7;
    unsigned wcol[64];
#pragma unroll
    for (int k2 = 0; k2 < 64; ++k2)
        wcol[k2] = packh2f(Wg[(2*k2)*128 + n], Wg[(2*k2+1)*128 + n]);
    const float bn = bias[n];
    for (int row0 = blockIdx.x * 4; row0 < rows; row0 += gridDim.x * 4) {
        if (tid < 256)
            rowbuf[tid] = ((const unsigned*)(in16 + (size_t)row0 * 128))[tid];
        __syncthreads();
        float a0 = bn, a1 = 0.f, a2 = 0.f, a3 = 0.f;
        const uint4* hr = (const uint4*)(rowbuf + rs * 64);
#pragma unroll
        for (int k8 = 0; k8 < 16; ++k8) {
            uint4 v = hr[k8];
            a0 = fdot2u(v.x, wcol[4*k8+0], a0);
            a1 = fdot2u(v.y, wcol[4*k8+1], a1);
            a2 = fdot2u(v.z, wcol[4*k8+2], a2);
            a3 = fdot2u(v.w, wcol[4*k8+3], a3);
        }
        float a = (a0 + a1) + (a2 + a3);
        if (RELU) a = fmaxf(a, 0.f);
        out16[(size_t)(row0 + rs) * 128 + n] = __float2half(a);
        __syncthreads();
    }
}

__global__ __launch_bounds__(512)
void k_l34(const __half* __restrict__ in16, const float* __restrict__ W3,
           const float* __restrict__ b3, const float* __restrict__ W4,
           const float* __restrict__ b4, float* __restrict__ out, int rows)
{
    __shared__ __align__(16) unsigned rowbuf[16 * 64];
    __shared__ __align__(16) unsigned short d3s[16 * 32];
    const int tid = threadIdx.x;
    const int n   = tid & 31;
    const int rs  = tid >> 5;
    unsigned w3col[64];
#pragma unroll
    for (int k2 = 0; k2 < 64; ++k2)
        w3col[k2] = packh2f(W3[(2*k2)*32 + n], W3[(2*k2+1)*32 + n]);
    unsigned w4p[16];
#pragma unroll
    for (int k2 = 0; k2 < 16; ++k2)
        w4p[k2] = packh2f(W4[2*k2], W4[2*k2+1]);
    const float b3n = b3[n], b4v = b4[0];
    for (int row0 = blockIdx.x * 16; row0 < rows; row0 += gridDim.x * 16) {
        rowbuf[tid]       = ((const unsigned*)(in16 + (size_t)row0 * 128))[tid];
        rowbuf[tid + 512] = ((const unsigned*)(in16 + (size_t)row0 * 128))[tid + 512];
        __syncthreads();
        float a0 = b3n, a1 = 0.f, a2 = 0.f, a3 = 0.f;
        const uint4* hr = (const uint4*)(rowbuf + rs * 64);
#pragma unroll
        for (int k8 = 0; k8 < 16; ++k8) {
            uint4 v = hr[k8];
            a0 = fdot2u(v.x, w3col[4*k8+0], a0);
            a1 = fdot2u(v.y, w3col[4*k8+1], a1);
            a2 = fdot2u(v.z, w3col[4*k8+2], a2);
            a3 = fdot2u(v.w, w3col[4*k8+3], a3);
        }
        float a = fmaxf((a0 + a1) + (a2 + a3), 0.f);
        d3s[rs * 32 + n] = __half_as_ushort(__float2half(a));
        __syncthreads();
        if (tid < 16) {
            const uint4* dp = (const uint4*)(d3s + tid * 32);
            float s0 = b4v, s1 = 0.f;
#pragma unroll
            for (int qq = 0; qq < 4; ++qq) {
                uint4 v = dp[qq];
                s0 = fdot2u(v.x, w4p[4*qq+0], s0);
                s1 = fdot2u(v.y, w4p[4*qq+1], s1);
                s0 = fdot2u(v.z, w4p[4*qq+2], s0);
                s1 = fdot2u(v.w, w4p[4*qq+3], s1);
            }
            out[row0 + tid] = sigmoidf_fast(s0 + s1);
        }
        __syncthreads();
    }
}

// ---------------------------------------------------------------------------
extern "C" void kernel_launch(void* const* d_in, const int* in_sizes, int n_in,
                              void* d_out, int out_size, void* d_ws, size_t ws_size,
                              hipStream_t stream)
{
    const float* x  = (const float*)d_in[0];
    const float* W  = (const float*)d_in[1];
    const float* U  = (const float*)d_in[2];
    const float* b  = (const float*)d_in[3];
    const float* W1 = (const float*)d_in[4];
    const float* b1 = (const float*)d_in[5];
    const float* W2 = (const float*)d_in[6];
    const float* b2 = (const float*)d_in[7];
    const float* W3 = (const float*)d_in[8];
    const float* b3 = (const float*)d_in[9];
    const float* W4 = (const float*)d_in[10];
    const float* b4 = (const float*)d_in[11];
    float* out = (float*)d_out;

    const int T    = 2048;
    const int rows = in_sizes[0] / 64;     // B*T
    const int B    = rows / T;             // 64

    char* ws = (char*)d_ws;
    const size_t xp_bytes = (size_t)rows * 512 * sizeof(__half);   // 128 MiB
    const size_t hs_bytes = (size_t)rows * 128 * sizeof(__half);   //  32 MiB

    if (ws_size >= xp_bytes + hs_bytes) {
        __half* xpT  = (__half*)ws;
        __half* hs16 = (__half*)(ws + xp_bytes);
        k_xprojT<<<B * 4, 512, 0, stream>>>(x, W, b, xpT, B, T);
        k_lstm4<<<B, 512, 0, stream>>>(U, xpT, hs16,
                                       W1, b1, W2, b2, W3, b3, W4, b4, out, T);
    } else {
        __half* hs16 = (__half*)ws;
        __half* d1   = (__half*)(ws + hs_bytes);
        __half* d2   = (__half*)ws;   // alias hs (dead after fc1)
        k_lstm_fused<<<B, 512, 0, stream>>>(U, x, W, b, hs16, T);
        k_fc128<false><<<1024, 512, 0, stream>>>(hs16, W1, b1, d1, rows);
        k_fc128<true ><<<1024, 512, 0, stream>>>(d1,  W2, b2, d2, rows);
        k_l34<<<1024, 512, 0, stream>>>(d2, W3, b3, W4, b4, out, rows);
    }
}

// Round 5
// 890.043 us; speedup vs baseline: 1.9605x; 1.1567x over previous
//
#include <hip/hip_runtime.h>
#include <hip/hip_fp16.h>
#include <cstdint>
#include <cstddef>

// ---------------------------------------------------------------------------
// helpers
// ---------------------------------------------------------------------------
typedef _Float16 hh2   __attribute__((ext_vector_type(2)));
typedef _Float16 f16x8 __attribute__((ext_vector_type(8)));
typedef float    f32x4 __attribute__((ext_vector_type(4)));

__device__ __forceinline__ float fdot2u(unsigned a, unsigned b, float c) {
#if __has_builtin(__builtin_amdgcn_fdot2)
    return __builtin_amdgcn_fdot2(__builtin_bit_cast(hh2, a),
                                  __builtin_bit_cast(hh2, b), c, false);
#else
    float r;
    asm("v_dot2_f32_f16 %0, %1, %2, %3" : "=v"(r) : "v"(a), "v"(b), "v"(c));
    return r;
#endif
}

__device__ __forceinline__ unsigned packh2f(float x, float y) {
    hh2 v; v.x = (_Float16)x; v.y = (_Float16)y;
    return __builtin_bit_cast(unsigned, v);
}

__device__ __forceinline__ float ex2(float x) {
#if __has_builtin(__builtin_amdgcn_exp2f)
    return __builtin_amdgcn_exp2f(x);
#else
    return exp2f(x);
#endif
}
// sigmoid: rcp(1+2^(-x*log2e)); x→-inf: exp2→inf, rcp(inf)=0 (no NaN)
__device__ __forceinline__ float sig2(float x) {
    return __builtin_amdgcn_rcpf(1.f + ex2(x * -1.442695041f));
}
// tanh(x) = 2*sigmoid(2x)-1, clamp-free (rcp(inf)=0 -> -1)
__device__ __forceinline__ float tanh2(float x) {
    return fmaf(2.f, __builtin_amdgcn_rcpf(1.f + ex2(x * -2.885390082f)), -1.f);
}
// legacy for fallback kernels
__device__ __forceinline__ float sigmoidf_fast(float x) {
    return __builtin_amdgcn_rcpf(1.f + __expf(-x));
}
__device__ __forceinline__ float tanhf_fast(float x) {
    float e = __expf(-2.f * fmaxf(x, -30.f));
    return (1.f - e) * __builtin_amdgcn_rcpf(1.f + e);
}

// raw barrier: drain LDS only, keep global loads in flight
#define BAR_LGKM() asm volatile("s_waitcnt lgkmcnt(0)\n\ts_barrier" ::: "memory")

// ---------------------------------------------------------------------------
// Kernel A: xpT = f16(x @ W + b) in chunked-transposed layout:
//   xpT[(row/8)][col][row%8]   (each [c8][col] cell = 8 halves = 16B)
// ---------------------------------------------------------------------------
__global__ __launch_bounds__(512, 2)
void k_xprojT(const float* __restrict__ x, const float* __restrict__ W,
              const float* __restrict__ bias, __half* __restrict__ xpT,
              int B, int T)
{
    __shared__ unsigned short xst[2][16 * 64];

    const int tid = threadIdx.x;
    const int w   = tid >> 6;
    const int l   = tid & 63;
    const int lj  = l & 15;
    const int hi  = l >> 4;
    const int bb  = blockIdx.x >> 2;
    const int q   = blockIdx.x & 3;

    f16x8 Wf[4][2];
    float bc[4];
#pragma unroll
    for (int cg = 0; cg < 4; ++cg) {
        const int col = cg * 128 + w * 16 + lj;
#pragma unroll
        for (int kk = 0; kk < 2; ++kk)
#pragma unroll
            for (int j = 0; j < 8; ++j)
                Wf[cg][kk][j] = (_Float16)W[(size_t)(kk*32 + hi*8 + j) * 512 + col];
        bc[cg] = bias[col];
    }

    const int nch = (T / 4) / 16;
    const size_t rowbase = (size_t)bb * T + (size_t)q * (T / 4);

    const int srow = tid >> 5;
    const int scp  = tid & 31;

    float2 xn = *(const float2*)(x + (rowbase + srow) * 64 + scp * 2);

    for (int ch = 0; ch < nch; ++ch) {
        unsigned pk = packh2f(xn.x, xn.y);
        *(unsigned*)((char*)xst[ch & 1] +
            (((srow * 128 + scp * 4)) ^ ((srow & 7) << 4))) = pk;
        if (ch + 1 < nch)
            xn = *(const float2*)(x + (rowbase + (ch+1)*16 + srow) * 64 + scp * 2);
        BAR_LGKM();

        f16x8 Axf[2];
#pragma unroll
        for (int kk = 0; kk < 2; ++kk)
            Axf[kk] = *(const f16x8*)((char*)xst[ch & 1] +
                ((lj * 128 + kk * 64 + hi * 16) ^ ((lj & 7) << 4)));

        const size_t c8base = (rowbase + (size_t)ch * 16) >> 3;
#pragma unroll
        for (int cg = 0; cg < 4; ++cg) {
            f32x4 C = {bc[cg], bc[cg], bc[cg], bc[cg]};
            C = __builtin_amdgcn_mfma_f32_16x16x32_f16(Axf[0], Wf[cg][0], C, 0, 0, 0);
            C = __builtin_amdgcn_mfma_f32_16x16x32_f16(Axf[1], Wf[cg][1], C, 0, 0, 0);
            const int col = cg * 128 + w * 16 + lj;
            uint2 u;
            u.x = packh2f(C[0], C[1]);
            u.y = packh2f(C[2], C[3]);
            const size_t hidx = ((c8base + (hi >> 1)) * 512 + col) * 8 + (hi & 1) * 4;
            *(uint2*)((unsigned short*)xpT + hidx) = u;
        }
        BAR_LGKM();
    }
}

// ---------------------------------------------------------------------------
// Kernel B: MFMA LSTM loop only (head extracted). One block per batch element,
// 512 threads. Per step/wave: 4 ds_read_b128 + 16 MFMA + lean exp2 acts +
// 1 ds_write_b16 + 1 raw barrier. Asymmetric wave priority ((w>>2)^w)&1
// gives exactly one prio-1 wave per SIMD under either wave->SIMD convention,
// staggering partner waves so act-phase hides under the partner's MFMA burst.
// ---------------------------------------------------------------------------
__global__ __launch_bounds__(512, 2)
void k_lstm5(const float* __restrict__ U, const __half* __restrict__ xpT,
             __half* __restrict__ hs, int T)
{
    __shared__ unsigned short hring[16][128];

    const int tid = threadIdx.x;
    const int w   = tid >> 6;
    const int l   = tid & 63;
    const int lj  = l & 15;
    const int hi  = l >> 4;
    const int bb  = blockIdx.x;

    f16x8 Bf[4][4];
#pragma unroll
    for (int g = 0; g < 4; ++g) {
        const int col = g * 128 + w * 16 + lj;
#pragma unroll
        for (int kk = 0; kk < 4; ++kk)
#pragma unroll
            for (int j = 0; j < 8; ++j)
                Bf[g][kk][j] = (_Float16)U[(size_t)(kk*32 + hi*8 + j) * 512 + col];
    }

    if (tid < 64) ((unsigned*)hring[15])[tid] = 0u;

    const uint4* __restrict__ xb = (const uint4*)xpT;
    const size_t xrow = (size_t)bb * (T / 8) * 512;
    int colg[4];
#pragma unroll
    for (int g = 0; g < 4; ++g) colg[g] = g * 128 + w * 16 + lj;

    uint4 qA[4], qB[4];
#pragma unroll
    for (int g = 0; g < 4; ++g) {
        qA[g] = xb[xrow + 0 * 512 + colg[g]];
        qB[g] = xb[xrow + 1 * 512 + colg[g]];
    }

    unsigned* __restrict__ hsw = (unsigned*)(hs + (size_t)bb * T * 128);
    float cst = 0.f;

    // exactly one elevated wave per SIMD whether SIMD id = w%4 or w>>1
    if (((w >> 2) ^ w) & 1) __builtin_amdgcn_s_setprio(1);

    f32x4 Cf[4] = {{0,0,0,0},{0,0,0,0},{0,0,0,0},{0,0,0,0}};

    BAR_LGKM();

    const int nbody = T / 16;
    for (int k = 0; k < nbody; ++k) {
#pragma unroll
        for (int p = 0; p < 16; ++p) {
            if (p == 2 && k > 0) {
                unsigned v = ((const unsigned*)hring[8])[tid];
                hsw[(size_t)(2*k - 1) * 512 + tid] = v;
            }
            if (p == 10) {
                unsigned v = ((const unsigned*)hring[0])[tid];
                hsw[(size_t)(2*k) * 512 + tid] = v;
            }
            if (p == 8) {
#pragma unroll
                for (int g = 0; g < 4; ++g)
                    qA[g] = xb[xrow + (size_t)(2*k + 2) * 512 + colg[g]];
            }

            const unsigned short* hrow = &hring[(p + 15) & 15][0];
            f16x8 Af[4];
#pragma unroll
            for (int kk = 0; kk < 4; ++kk)
                Af[kk] = *(const f16x8*)(hrow + kk * 32 + hi * 8);

            // seed elem 0 of each accumulator with z (= xp value)
#pragma unroll
            for (int g = 0; g < 4; ++g) {
                const uint4 qq = (p < 8) ? qA[g] : qB[g];
                const int wsel = (p & 7) >> 1;
                unsigned uw = (wsel == 0) ? qq.x : (wsel == 1) ? qq.y
                            : (wsel == 2) ? qq.z : qq.w;
                __half2 hh = __builtin_bit_cast(__half2, uw);
                Cf[g][0] = __half2float((p & 1) ? __high2half(hh) : __low2half(hh));
            }
#pragma unroll
            for (int kk = 0; kk < 4; ++kk)
#pragma unroll
                for (int g = 0; g < 4; ++g)
                    Cf[g] = __builtin_amdgcn_mfma_f32_16x16x32_f16(Af[kk], Bf[g][kk], Cf[g], 0, 0, 0);

            float iv = sig2(Cf[0][0]);
            float fv = sig2(Cf[1][0]);
            float gv = tanh2(Cf[2][0]);
            float ov = sig2(Cf[3][0]);
            cst = fmaf(fv, cst, iv * gv);
            float h = ov * tanh2(cst);

            if (l < 16)
                hring[p][w * 16 + lj] = __half_as_ushort(__float2half(h));

            if (p == 15) {
#pragma unroll
                for (int g = 0; g < 4; ++g)
                    qB[g] = xb[xrow + (size_t)(2*k + 3) * 512 + colg[g]];
            }
            BAR_LGKM();
        }
    }
    {
        unsigned v = ((const unsigned*)hring[8])[tid];
        hsw[(size_t)(T/8 - 1) * 512 + tid] = v;
    }
}

// ---------------------------------------------------------------------------
// Kernel C: dense head, wide (256 CUs). Block = (batch, chunk-group of 4).
// Per 16-row chunk: stage hs -> d1 -> relu d2 -> relu d3 -> sigmoid d4 -> out.
// ---------------------------------------------------------------------------
__global__ __launch_bounds__(512, 2)
void k_head(const __half* __restrict__ hs,
            const float* __restrict__ W1, const float* __restrict__ b1,
            const float* __restrict__ W2, const float* __restrict__ b2,
            const float* __restrict__ W3, const float* __restrict__ b3,
            const float* __restrict__ W4, const float* __restrict__ b4,
            float* __restrict__ out, int T)
{
    __shared__ unsigned short hstage[16 * 128];
    __shared__ unsigned short d1buf[16 * 128];
    __shared__ unsigned short d2buf[16 * 128];
    __shared__ unsigned short d3buf[16 * 40];

    const int tid = threadIdx.x;
    const int w   = tid >> 6;
    const int l   = tid & 63;
    const int lj  = l & 15;
    const int hi  = l >> 4;
    const int bb  = blockIdx.x >> 5;
    const int ch0 = (blockIdx.x & 31) * 4;

    const int col1 = w * 16 + lj;
    const int col3 = (w & 1) * 16 + lj;

    f16x8 W1f[4], W2f[4], W3f[4];
#pragma unroll
    for (int kk = 0; kk < 4; ++kk)
#pragma unroll
        for (int j = 0; j < 8; ++j) {
            W1f[kk][j] = (_Float16)W1[(size_t)(kk*32 + hi*8 + j) * 128 + col1];
            W2f[kk][j] = (_Float16)W2[(size_t)(kk*32 + hi*8 + j) * 128 + col1];
            W3f[kk][j] = (_Float16)W3[(size_t)(kk*32 + hi*8 + j) * 32 + col3];
        }
    const float b1c = b1[col1];
    const float b2c = b2[col1];
    const float b3c = b3[col3];
    unsigned w4p[16];
#pragma unroll
    for (int k2 = 0; k2 < 16; ++k2)
        w4p[k2] = packh2f(W4[2*k2], W4[2*k2 + 1]);
    const float b4v = b4[0];

    const __half* __restrict__ hsb = hs + (size_t)bb * T * 128;
    const int srow = tid >> 5;
    const int scp  = tid & 31;

    for (int ch = ch0; ch < ch0 + 4; ++ch) {
        const int t0 = ch * 16;
        uint2 hv = *(const uint2*)(hsb + (size_t)(t0 + srow) * 128 + scp * 4);
        *(uint2*)((char*)hstage + ((srow * 256 + scp * 8) ^ ((srow & 7) << 4))) = hv;
        __syncthreads();

        f16x8 A[4];
#pragma unroll
        for (int kk = 0; kk < 4; ++kk)
            A[kk] = *(const f16x8*)((char*)hstage +
                ((lj * 256 + kk * 64 + hi * 16) ^ ((lj & 7) << 4)));
        f32x4 C1 = {b1c, b1c, b1c, b1c};
#pragma unroll
        for (int kk = 0; kk < 4; ++kk)
            C1 = __builtin_amdgcn_mfma_f32_16x16x32_f16(A[kk], W1f[kk], C1, 0, 0, 0);
#pragma unroll
        for (int r = 0; r < 4; ++r) {
            const int row = hi * 4 + r;
            *(unsigned short*)((char*)d1buf + ((row * 256 + col1 * 2) ^ ((row & 7) << 4))) =
                __half_as_ushort(__float2half(C1[r]));
        }
        __syncthreads();

#pragma unroll
        for (int kk = 0; kk < 4; ++kk)
            A[kk] = *(const f16x8*)((char*)d1buf +
                ((lj * 256 + kk * 64 + hi * 16) ^ ((lj & 7) << 4)));
        f32x4 C2 = {b2c, b2c, b2c, b2c};
#pragma unroll
        for (int kk = 0; kk < 4; ++kk)
            C2 = __builtin_amdgcn_mfma_f32_16x16x32_f16(A[kk], W2f[kk], C2, 0, 0, 0);
#pragma unroll
        for (int r = 0; r < 4; ++r) {
            const int row = hi * 4 + r;
            *(unsigned short*)((char*)d2buf + ((row * 256 + col1 * 2) ^ ((row & 7) << 4))) =
                __half_as_ushort(__float2half(fmaxf(C2[r], 0.f)));
        }
        __syncthreads();

#pragma unroll
        for (int kk = 0; kk < 4; ++kk)
            A[kk] = *(const f16x8*)((char*)d2buf +
                ((lj * 256 + kk * 64 + hi * 16) ^ ((lj & 7) << 4)));
        f32x4 C3 = {b3c, b3c, b3c, b3c};
#pragma unroll
        for (int kk = 0; kk < 4; ++kk)
            C3 = __builtin_amdgcn_mfma_f32_16x16x32_f16(A[kk], W3f[kk], C3, 0, 0, 0);
        if (w < 2) {
#pragma unroll
            for (int r = 0; r < 4; ++r) {
                const int row = hi * 4 + r;
                d3buf[row * 40 + col3] =
                    __half_as_ushort(__float2half(fmaxf(C3[r], 0.f)));
            }
        }
        __syncthreads();

        if (w == 0 && l < 16) {
            const unsigned short* dr = &d3buf[l * 40];
            float s0 = b4v, s1 = 0.f;
#pragma unroll
            for (int qq = 0; qq < 4; ++qq) {
                uint4 v = *(const uint4*)(dr + qq * 8);
                s0 = fdot2u(v.x, w4p[qq*4 + 0], s0);
                s1 = fdot2u(v.y, w4p[qq*4 + 1], s1);
                s0 = fdot2u(v.z, w4p[qq*4 + 2], s0);
                s1 = fdot2u(v.w, w4p[qq*4 + 3], s1);
            }
            out[(size_t)bb * T + t0 + l] = sigmoidf_fast(s0 + s1);
        }
        __syncthreads();
    }
}

// ---------------------------------------------------------------------------
// Fallback path (small workspace): round-1 fused dot2 LSTM + dot2 head.
// ---------------------------------------------------------------------------
__global__ __launch_bounds__(512)
void k_lstm_fused(const float* __restrict__ U, const float* __restrict__ x,
                  const float* __restrict__ W, const float* __restrict__ bias,
                  __half* __restrict__ hs, int T)
{
    __shared__ __align__(16) unsigned hbuf[64];
    __shared__ float act[512];
    __shared__ __align__(16) unsigned xrow[32];

    const int g    = threadIdx.x;
    const int bb   = blockIdx.x;
    const int j    = g & 127;
    const int gate = g >> 7;

    unsigned ucol[64];
#pragma unroll
    for (int k2 = 0; k2 < 64; ++k2)
        ucol[k2] = packh2f(U[(2*k2)*512 + g], U[(2*k2+1)*512 + g]);
    unsigned wcol[32];
#pragma unroll
    for (int k2 = 0; k2 < 32; ++k2)
        wcol[k2] = packh2f(W[(2*k2)*512 + g], W[(2*k2+1)*512 + g]);
    const float bg = bias[g];
    const float2* __restrict__ xb2 = (const float2*)(x + (size_t)bb * T * 64);
    if (g < 32) { float2 x0 = xb2[g]; xrow[g] = packh2f(x0.x, x0.y); }
    if (g < 64) hbuf[g] = 0u;
    float c = 0.f;
    __half* __restrict__ hsb = hs + (size_t)bb * T * 128;
    __syncthreads();

    for (int t = 0; t < T; ++t) {
        float2 xn = make_float2(0.f, 0.f);
        if (g < 32 && t + 1 < T) xn = xb2[(size_t)(t + 1) * 32 + g];
        float a0 = bg, a1 = 0.f, a2 = 0.f, a3 = 0.f;
        const uint4* hr = (const uint4*)hbuf;
#pragma unroll
        for (int k8 = 0; k8 < 16; ++k8) {
            uint4 v = hr[k8];
            a0 = fdot2u(v.x, ucol[4*k8+0], a0);
            a1 = fdot2u(v.y, ucol[4*k8+1], a1);
            a2 = fdot2u(v.z, ucol[4*k8+2], a2);
            a3 = fdot2u(v.w, ucol[4*k8+3], a3);
        }
        const uint4* xr = (const uint4*)xrow;
#pragma unroll
        for (int k8 = 0; k8 < 8; ++k8) {
            uint4 v = xr[k8];
            a0 = fdot2u(v.x, wcol[4*k8+0], a0);
            a1 = fdot2u(v.y, wcol[4*k8+1], a1);
            a2 = fdot2u(v.z, wcol[4*k8+2], a2);
            a3 = fdot2u(v.w, wcol[4*k8+3], a3);
        }
        float z = (a0 + a1) + (a2 + a3);
        float a = (gate == 2) ? tanhf_fast(z) : sigmoidf_fast(z);
        act[g] = a;
        __syncthreads();
        float iv = act[j], fv = act[j + 128], gv = act[j + 256], ov = act[j + 384];
        c = fmaf(fv, c, iv * gv);
        float h = ov * tanhf_fast(c);
        if (gate == 0) {
            ((unsigned short*)hbuf)[j] = __half_as_ushort(__float2half(h));
            hsb[(size_t)t * 128 + j] = __float2half(h);
        }
        if (g < 32 && t + 1 < T) xrow[g] = packh2f(xn.x, xn.y);
        __syncthreads();
    }
}

template<bool RELU>
__global__ __launch_bounds__(512)
void k_fc128(const __half* __restrict__ in16, const float* __restrict__ Wg,
             const float* __restrict__ bias, __half* __restrict__ out16, int rows)
{
    __shared__ __align__(16) unsigned rowbuf[4 * 64];
    const int tid = threadIdx.x;
    const int n   = tid & 127;
    const int rs  = tid >> 7;
    unsigned wcol[64];
#pragma unroll
    for (int k2 = 0; k2 < 64; ++k2)
        wcol[k2] = packh2f(Wg[(2*k2)*128 + n], Wg[(2*k2+1)*128 + n]);
    const float bn = bias[n];
    for (int row0 = blockIdx.x * 4; row0 < rows; row0 += gridDim.x * 4) {
        if (tid < 256)
            rowbuf[tid] = ((const unsigned*)(in16 + (size_t)row0 * 128))[tid];
        __syncthreads();
        float a0 = bn, a1 = 0.f, a2 = 0.f, a3 = 0.f;
        const uint4* hr = (const uint4*)(rowbuf + rs * 64);
#pragma unroll
        for (int k8 = 0; k8 < 16; ++k8) {
            uint4 v = hr[k8];
            a0 = fdot2u(v.x, wcol[4*k8+0], a0);
            a1 = fdot2u(v.y, wcol[4*k8+1], a1);
            a2 = fdot2u(v.z, wcol[4*k8+2], a2);
            a3 = fdot2u(v.w, wcol[4*k8+3], a3);
        }
        float a = (a0 + a1) + (a2 + a3);
        if (RELU) a = fmaxf(a, 0.f);
        out16[(size_t)(row0 + rs) * 128 + n] = __float2half(a);
        __syncthreads();
    }
}

__global__ __launch_bounds__(512)
void k_l34(const __half* __restrict__ in16, const float* __restrict__ W3,
           const float* __restrict__ b3, const float* __restrict__ W4,
           const float* __restrict__ b4, float* __restrict__ out, int rows)
{
    __shared__ __align__(16) unsigned rowbuf[16 * 64];
    __shared__ __align__(16) unsigned short d3s[16 * 32];
    const int tid = threadIdx.x;
    const int n   = tid & 31;
    const int rs  = tid >> 5;
    unsigned w3col[64];
#pragma unroll
    for (int k2 = 0; k2 < 64; ++k2)
        w3col[k2] = packh2f(W3[(2*k2)*32 + n], W3[(2*k2+1)*32 + n]);
    unsigned w4p[16];
#pragma unroll
    for (int k2 = 0; k2 < 16; ++k2)
        w4p[k2] = packh2f(W4[2*k2], W4[2*k2+1]);
    const float b3n = b3[n], b4v = b4[0];
    for (int row0 = blockIdx.x * 16; row0 < rows; row0 += gridDim.x * 16) {
        rowbuf[tid]       = ((const unsigned*)(in16 + (size_t)row0 * 128))[tid];
        rowbuf[tid + 512] = ((const unsigned*)(in16 + (size_t)row0 * 128))[tid + 512];
        __syncthreads();
        float a0 = b3n, a1 = 0.f, a2 = 0.f, a3 = 0.f;
        const uint4* hr = (const uint4*)(rowbuf + rs * 64);
#pragma unroll
        for (int k8 = 0; k8 < 16; ++k8) {
            uint4 v = hr[k8];
            a0 = fdot2u(v.x, w3col[4*k8+0], a0);
            a1 = fdot2u(v.y, w3col[4*k8+1], a1);
            a2 = fdot2u(v.z, w3col[4*k8+2], a2);
            a3 = fdot2u(v.w, w3col[4*k8+3], a3);
        }
        float a = fmaxf((a0 + a1) + (a2 + a3), 0.f);
        d3s[rs * 32 + n] = __half_as_ushort(__float2half(a));
        __syncthreads();
        if (tid < 16) {
            const uint4* dp = (const uint4*)(d3s + tid * 32);
            float s0 = b4v, s1 = 0.f;
#pragma unroll
            for (int qq = 0; qq < 4; ++qq) {
                uint4 v = dp[qq];
                s0 = fdot2u(v.x, w4p[4*qq+0], s0);
                s1 = fdot2u(v.y, w4p[4*qq+1], s1);
                s0 = fdot2u(v.z, w4p[4*qq+2], s0);
                s1 = fdot2u(v.w, w4p[4*qq+3], s1);
            }
            out[row0 + tid] = sigmoidf_fast(s0 + s1);
        }
        __syncthreads();
    }
}

// ---------------------------------------------------------------------------
extern "C" void kernel_launch(void* const* d_in, const int* in_sizes, int n_in,
                              void* d_out, int out_size, void* d_ws, size_t ws_size,
                              hipStream_t stream)
{
    const float* x  = (const float*)d_in[0];
    const float* W  = (const float*)d_in[1];
    const float* U  = (const float*)d_in[2];
    const float* b  = (const float*)d_in[3];
    const float* W1 = (const float*)d_in[4];
    const float* b1 = (const float*)d_in[5];
    const float* W2 = (const float*)d_in[6];
    const float* b2 = (const float*)d_in[7];
    const float* W3 = (const float*)d_in[8];
    const float* b3 = (const float*)d_in[9];
    const float* W4 = (const float*)d_in[10];
    const float* b4 = (const float*)d_in[11];
    float* out = (float*)d_out;

    const int T    = 2048;
    const int rows = in_sizes[0] / 64;     // B*T
    const int B    = rows / T;             // 64

    char* ws = (char*)d_ws;
    const size_t xp_bytes = (size_t)rows * 512 * sizeof(__half);   // 128 MiB
    const size_t hs_bytes = (size_t)rows * 128 * sizeof(__half);   //  32 MiB

    if (ws_size >= xp_bytes + hs_bytes) {
        __half* xpT  = (__half*)ws;
        __half* hs16 = (__half*)(ws + xp_bytes);
        k_xprojT<<<B * 4, 512, 0, stream>>>(x, W, b, xpT, B, T);
        k_lstm5<<<B, 512, 0, stream>>>(U, xpT, hs16, T);
        k_head<<<B * 32, 512, 0, stream>>>(hs16, W1, b1, W2, b2, W3, b3,
                                           W4, b4, out, T);
    } else {
        __half* hs16 = (__half*)ws;
        __half* d1   = (__half*)(ws + hs_bytes);
        __half* d2   = (__half*)ws;   // alias hs (dead after fc1)
        k_lstm_fused<<<B, 512, 0, stream>>>(U, x, W, b, hs16, T);
        k_fc128<false><<<1024, 512, 0, stream>>>(hs16, W1, b1, d1, rows);
        k_fc128<true ><<<1024, 512, 0, stream>>>(d1,  W2, b2, d2, rows);
        k_l34<<<1024, 512, 0, stream>>>(d2, W3, b3, W4, b4, out, rows);
    }
}